// Round 21
// baseline (794.293 us; speedup 1.0000x reference)
//
#include <hip/hip_runtime.h>

#define H 128
#define F_IN 16
#define BNEPS 1e-5f

typedef __attribute__((ext_vector_type(8))) short short8;
typedef __attribute__((ext_vector_type(4))) float f32x4;

// f32 -> bf16 round-to-nearest-even
__device__ __forceinline__ unsigned short f2bf(float f)
{
    unsigned u = __builtin_bit_cast(unsigned, f);
    u += 0x7FFFu + ((u >> 16) & 1u);
    return (unsigned short)(u >> 16);
}
__device__ __forceinline__ float bf2f(unsigned short h)
{
    return __builtin_bit_cast(float, (unsigned)h << 16);
}

// BN affine params for feature j: s[j], t[j] (identity if S==nullptr)
__device__ __forceinline__ void bn_param(const float* __restrict__ S,
                                         const float* __restrict__ g,
                                         const float* __restrict__ b,
                                         float invM, int j,
                                         float* __restrict__ sS, float* __restrict__ sT)
{
    float s = 1.f, tt = 0.f;
    if (S) {
        float mean = S[j] * invM;
        float var  = S[H + j] * invM - mean * mean;
        s  = rsqrtf(var + BNEPS) * g[j];
        tt = b[j] - mean * s;
    }
    sS[j] = s;
    sT[j] = tt;
}

// ---------------------------------------------------------------------------
// 512-thread staging: 64x128 bf16 tile with per-feature affine into swizzled
// LDS. element (row,k) -> ushort idx row*128 + (k ^ ((row&7)<<3))
__device__ __forceinline__ void stage_aff(const unsigned short* __restrict__ src,
                                          unsigned short* sA, int r0, int M, int t,
                                          const float* __restrict__ sS,
                                          const float* __restrict__ sT)
{
#pragma unroll
    for (int i = 0; i < 2; ++i) {
        int cid  = t + 512 * i;
        int row  = cid >> 4;
        int ck   = cid & 15;
        int grow = r0 + row;
        short8 v = (short8)0;
        if (grow < M) {
            v = *(const short8*)(src + (size_t)grow * H + ck * 8);
            int j0 = ck * 8;
#pragma unroll
            for (int j = 0; j < 8; ++j)
                v[j] = (short)f2bf(bf2f((unsigned short)v[j]) * sS[j0 + j] + sT[j0 + j]);
        }
        *(short8*)(sA + (row << 7) + ((ck ^ (row & 7)) << 3)) = v;
    }
}

// Gather variant: tile row i holds src[idx[p0+i]], same affine.
__device__ __forceinline__ void stage_aff_gather(const unsigned short* __restrict__ src,
                                                 const int* __restrict__ idx,
                                                 unsigned short* sA, int p0, int M, int t,
                                                 const float* __restrict__ sS,
                                                 const float* __restrict__ sT)
{
#pragma unroll
    for (int i = 0; i < 2; ++i) {
        int cid = t + 512 * i;
        int row = cid >> 4;
        int ck  = cid & 15;
        int p   = p0 + row;
        short8 v = (short8)0;
        if (p < M) {
            v = *(const short8*)(src + (size_t)idx[p] * H + ck * 8);
            int j0 = ck * 8;
#pragma unroll
            for (int j = 0; j < 8; ++j)
                v[j] = (short)f2bf(bf2f((unsigned short)v[j]) * sS[j0 + j] + sT[j0 + j]);
        }
        *(short8*)(sA + (row << 7) + ((ck ^ (row & 7)) << 3)) = v;
    }
}

// aggsum holds per-node MEANS -> convert to bf16; then zero rows for next layer
__device__ __forceinline__ void stage_agg_bf16(float* __restrict__ aggsum,
                                               unsigned short* sA, int r0, int M, int t)
{
#pragma unroll
    for (int i = 0; i < 2; ++i) {
        int cid  = t + 512 * i;
        int row  = cid >> 4;
        int ck   = cid & 15;
        int grow = r0 + row;
        short8 ph = (short8)0;
        if (grow < M) {
            float4* q = (float4*)(aggsum + (size_t)grow * H + ck * 8);
            float4 a = q[0], b = q[1];
            float xs[8] = {a.x, a.y, a.z, a.w, b.x, b.y, b.z, b.w};
#pragma unroll
            for (int j = 0; j < 8; ++j) ph[j] = (short)f2bf(xs[j]);
            q[0] = make_float4(0.f, 0.f, 0.f, 0.f);
            q[1] = make_float4(0.f, 0.f, 0.f, 0.f);
        }
        *(short8*)(sA + (row << 7) + ((ck ^ (row & 7)) << 3)) = ph;
    }
}

// ---------------------------------------------------------------------------
// One-time weight bf16 fragment precompute (21 matrices, unscaled).
__global__ __launch_bounds__(256) void wbf16_kernel(const float* __restrict__ edge_w,
                                                    const float* __restrict__ n1_w,
                                                    const float* __restrict__ n2_w,
                                                    short8* __restrict__ out)
{
    int m = blockIdx.x;
    int layer = m / 7, k = m % 7;
    const float* W = (k < 3) ? edge_w + (size_t)layer * 384 * H + (size_t)k * H * H
                   : (k < 5) ? n1_w + (size_t)layer * 256 * H + (size_t)(k - 3) * H * H
                             : n2_w + (size_t)layer * 256 * H + (size_t)(k - 5) * H * H;
    short8* oh = out + (size_t)m * 2048;
    for (int e = threadIdx.x; e < 2048; e += 256) {
        int jbB = e >> 9, s = (e >> 7) & 3, c = (e >> 6) & 1, lane = e & 63;
        int g = lane >> 4, c0 = lane & 15;
        short8 hi;
#pragma unroll
        for (int j = 0; j < 8; ++j)
            hi[j] = (short)f2bf(W[(size_t)(32 * s + 8 * g + j) * H + jbB * 32 + 16 * c + c0]);
        oh[e] = hi;
    }
}

// Wave w (0..7) owns cols [16w,16w+16): fragment idx jbB=w>>1, cB=w&1.
__device__ __forceinline__ void load_wfrag_h(const short8* __restrict__ Wp, int w,
                                             int lane, short8 wf[4])
{
    int base = ((w >> 1) * 8 + (w & 1)) * 64 + lane;
#pragma unroll
    for (int s = 0; s < 4; ++s)
        wf[s] = Wp[base + s * 128];
}

// acc[fr] += sA(64x128 bf16, swizzled) @ Wf(128x16 bf16)   (16 MFMA)
__device__ __forceinline__ void mfma_gemm_h(const unsigned short* sA, const short8 wf[4],
                                            f32x4 acc[4], int lane)
{
    const int g = lane >> 4, r = lane & 15;
#pragma unroll
    for (int s = 0; s < 4; ++s) {
        short8 a4[4];
#pragma unroll
        for (int fr = 0; fr < 4; ++fr) {
            int row = 16 * fr + r;
            int ck  = (4 * s + g) ^ (row & 7);
            a4[fr] = *(const short8*)(sA + (row << 7) + (ck << 3));
        }
#pragma unroll
        for (int fr = 0; fr < 4; ++fr)
            acc[fr] = __builtin_amdgcn_mfma_f32_16x16x32_bf16(a4[fr], wf[s], acc[fr], 0, 0, 0);
    }
}

__device__ __forceinline__ void zero_acc_h(f32x4 acc[4])
{
#pragma unroll
    for (int fr = 0; fr < 4; ++fr) {
        acc[fr][0] = 0.f; acc[fr][1] = 0.f; acc[fr][2] = 0.f; acc[fr][3] = 0.f;
    }
}

// ---------------------------------------------------------------------------
// One-time sort machinery (edge_index is layer-invariant)
__global__ __launch_bounds__(256) void hist_kernel(const int* __restrict__ col,
                                                   int* __restrict__ cnt, int E)
{
    int e = blockIdx.x * 256 + threadIdx.x;
    if (e < E) atomicAdd(&cnt[col[e]], 1);
}

__global__ __launch_bounds__(1024) void scan_kernel(const int* __restrict__ cnt,
                                                    int* __restrict__ offs, int Nn)
{
    __shared__ int ls[1024];
    int t = threadIdx.x;
    int per = (Nn + 1023) / 1024;
    int base = t * per;
    int s = 0;
    for (int k = 0; k < per; ++k) {
        int i = base + k;
        if (i < Nn) s += cnt[i];
    }
    ls[t] = s;
    __syncthreads();
    for (int d = 1; d < 1024; d <<= 1) {
        int u = (t >= d) ? ls[t - d] : 0;
        __syncthreads();
        ls[t] += u;
        __syncthreads();
    }
    int run = ls[t] - s;
    for (int k = 0; k < per; ++k) {
        int i = base + k;
        if (i < Nn) {
            offs[i] = run;
            run += cnt[i];
        }
    }
}

__global__ __launch_bounds__(256) void scatter_kernel(const int* __restrict__ row,
                                                      const int* __restrict__ col,
                                                      const int* __restrict__ offs,
                                                      int* __restrict__ tmpc,
                                                      int* __restrict__ sortedIds,
                                                      int* __restrict__ rowS,
                                                      int* __restrict__ colS, int E)
{
    int e = blockIdx.x * 256 + threadIdx.x;
    if (e < E) {
        int c = col[e];
        int p = offs[c] + atomicAdd(&tmpc[c], 1);
        sortedIds[p] = e;
        rowS[p] = row[e];
        colS[p] = c;
    }
}

// ---------------------------------------------------------------------------
// Encoder: out(bf16) = relu(X[M,16] @ W[16,128] + b)
__global__ __launch_bounds__(256) void enc_kernel(const float* __restrict__ X,
                                                  const float* __restrict__ W,
                                                  const float* __restrict__ bias,
                                                  unsigned short* __restrict__ out, int M)
{
    __shared__ float sW[F_IN * H];
    __shared__ float sb[H];
    int t = threadIdx.x;
    reinterpret_cast<float4*>(sW)[t]       = reinterpret_cast<const float4*>(W)[t];
    reinterpret_cast<float4*>(sW)[t + 256] = reinterpret_cast<const float4*>(W)[t + 256];
    if (t < H) sb[t] = bias[t];
    __syncthreads();
    int row = blockIdx.x * 2 + (t >> 7);
    if (row >= M) return;
    int j = t & 127;
    float acc = sb[j];
#pragma unroll
    for (int k = 0; k < F_IN; ++k)
        acc += X[(size_t)row * F_IN + k] * sW[k * H + j];
    out[(size_t)row * H + j] = f2bf(fmaxf(acc, 0.f));
}

// Gather-encoder: out[p](bf16) = relu(X[sortedIds[p],16] @ W + b)
__global__ __launch_bounds__(256) void enc_gather_kernel(const float* __restrict__ X,
                                                         const int* __restrict__ sortedIds,
                                                         const float* __restrict__ W,
                                                         const float* __restrict__ bias,
                                                         unsigned short* __restrict__ out,
                                                         int M)
{
    __shared__ float sW[F_IN * H];
    __shared__ float sb[H];
    int t = threadIdx.x;
    reinterpret_cast<float4*>(sW)[t]       = reinterpret_cast<const float4*>(W)[t];
    reinterpret_cast<float4*>(sW)[t + 256] = reinterpret_cast<const float4*>(W)[t + 256];
    if (t < H) sb[t] = bias[t];
    __syncthreads();
    int p = blockIdx.x * 2 + (t >> 7);
    if (p >= M) return;
    int src = sortedIds[p];
    int j = t & 127;
    float acc = sb[j];
#pragma unroll
    for (int k = 0; k < F_IN; ++k)
        acc += X[(size_t)src * F_IN + k] * sW[k * H + j];
    out[(size_t)p * H + j] = f2bf(fmaxf(acc, 0.f));
}

// ---------------------------------------------------------------------------
// Fused edge kernel, 512 threads (8 waves x 16-col strips):
//   e'[p] = relu(bn_e(e[p])@W3 + bn_h(h[rowS])@W1 + bn_h(h[colS])@W2 + be)
//   m     = relu(e'@U2 + bn_h(h[rowS])@U1 + b1)
//   aggsum[col] += register-level segment-MEAN partials ; fused e'-stats
//   e' written to global via coalesced LDS stage-out.
__global__ __launch_bounds__(512, 3) void edge_kernel(unsigned short* eb,
                                                      const int* __restrict__ rowS,
                                                      const int* __restrict__ colS,
                                                      const int* __restrict__ cnt,
                                                      const unsigned short* __restrict__ hb,
                                                      const short8* __restrict__ wfrL,
                                                      const float* __restrict__ be,
                                                      const float* __restrict__ b1,
                                                      float* __restrict__ aggsum, int E,
                                                      const float* __restrict__ Sh,
                                                      const float* __restrict__ gh,
                                                      const float* __restrict__ bh,
                                                      float invN,
                                                      const float* __restrict__ Se,
                                                      const float* __restrict__ ge,
                                                      const float* __restrict__ beB,
                                                      float invE,
                                                      float* __restrict__ eStats)
{
    __shared__ __align__(16) unsigned char smem[64 * 128 * 6 + 256 + 256 + 2048];
    unsigned short* sE  = (unsigned short*)smem;          // 16 KB  e (bf16)
    unsigned short* sHt = sE + 64 * 128;                  // 16 KB  h[rowS] (bf16)
    unsigned short* sHc = sHt + 64 * 128;                 // 16 KB  h[colS] (bf16)
    int*            scol = (int*)(smem + 64 * 128 * 6);          // 256 B
    float*          sinv = (float*)(smem + 64 * 128 * 6 + 256);  // 256 B
    float*          bnp  = (float*)(smem + 64 * 128 * 6 + 512);  // 2 KB

    const int t = threadIdx.x, lane = t & 63, w = t >> 6;
    const int e0 = blockIdx.x * 64;
    const int g = lane >> 4, c0 = lane & 15;
    const int j = 16 * w + c0;        // this lane's output column

    if (t < 64) {
        int cc = colS[(e0 + t < E) ? (e0 + t) : (E - 1)];
        scol[t] = cc;
        int c = cnt[cc];
        sinv[t] = 1.f / (float)(c > 1 ? c : 1);
    }
    if (t >= 64 && t < 192)      bn_param(Sh, gh, bh, invN, t - 64, bnp, bnp + 128);
    else if (t >= 192 && t < 320) bn_param(Se, ge, beB, invE, t - 192, bnp + 256, bnp + 384);
    __syncthreads();   // bnp + scol ready

    stage_aff(eb, sE, e0, E, t, bnp + 256, bnp + 384);
    stage_aff_gather(hb, rowS, sHt, e0, E, t, bnp, bnp + 128);
    {
        int Mt = E - e0; if (Mt > 64) Mt = 64;
        stage_aff_gather(hb, scol, sHc, 0, Mt, t, bnp, bnp + 128);
    }

    short8 wf[4];
    f32x4 acc[4];
    zero_acc_h(acc);
    load_wfrag_h(wfrL + 2 * 2048, w, lane, wf);   // W3
    __syncthreads();
    mfma_gemm_h(sE, wf, acc, lane);
    load_wfrag_h(wfrL + 0 * 2048, w, lane, wf);   // W1
    mfma_gemm_h(sHt, wf, acc, lane);
    load_wfrag_h(wfrL + 1 * 2048, w, lane, wf);   // W2 (B-term)
    mfma_gemm_h(sHc, wf, acc, lane);
    __syncthreads();   // all reads of sE done -> safe to overwrite with e'

    // epilogue 1: e' = relu(acc + be) -> sE (swizzled) + stats in registers
    float s1 = 0.f, s2 = 0.f;
    {
        float bej = be[j];
#pragma unroll
        for (int fr = 0; fr < 4; ++fr)
#pragma unroll
            for (int r = 0; r < 4; ++r) {
                int Rl = 16 * fr + 4 * g + r;
                int p  = e0 + Rl;
                float v = acc[fr][r] + bej;
                v = fmaxf(v, 0.f);
                unsigned short vb = f2bf(v);
                if (p < E) {
                    s1 += v;
                    s2 += v * v;
                }
                sE[(Rl << 7) + (j ^ ((Rl & 7) << 3))] = vb;
            }
    }
    __syncthreads();   // sE complete

    // coalesced e' stage-out: 2 x 16B stores per thread (reads sE, unswizzled)
#pragma unroll
    for (int i = 0; i < 2; ++i) {
        int cid = t + 512 * i;
        int row = cid >> 4;
        int ck  = cid & 15;
        int p   = e0 + row;
        if (p < E) {
            short8 v = *(const short8*)(sE + (row << 7) + ((ck ^ (row & 7)) << 3));
            *(short8*)(eb + (size_t)p * H + ck * 8) = v;
        }
    }

    // GEMM2: m = e'@U2 + bn_h(h[rowS])@U1
    zero_acc_h(acc);
    load_wfrag_h(wfrL + 4 * 2048, w, lane, wf);   // U2
    mfma_gemm_h(sE, wf, acc, lane);
    load_wfrag_h(wfrL + 3 * 2048, w, lane, wf);   // U1
    mfma_gemm_h(sHt, wf, acc, lane);

    // epilogue 2: register-level segment reduction. Thread holds rows
    // {16fr+4g+r, r=0..3} (4 consecutive-row runs) for col j; emit mean
    // partials per segment directly from acc (no LDS round-trip, no barrier).
    {
        float b1j = b1[j];
        int rlim = E - e0;
#pragma unroll
        for (int fr = 0; fr < 4; ++fr) {
            int base = 16 * fr + 4 * g;
            float run = 0.f;
            int cur = scol[base];
#pragma unroll
            for (int r = 0; r < 4; ++r) {
                int row = base + r;
                int cc = scol[row];
                if (cc != cur) {
                    if (run != 0.f)
                        atomicAdd(&aggsum[(size_t)cur * H + j], run * sinv[row - 1]);
                    run = 0.f;
                    cur = cc;
                }
                if (row < rlim) {
                    float v = fmaxf(acc[fr][r] + b1j, 0.f);
                    run += v;
                }
            }
            if (run != 0.f)
                atomicAdd(&aggsum[(size_t)cur * H + j], run * sinv[base + 3]);
        }
    }

    // fused e'-stats
    {
        float a = s1, b = s2;
        a += __shfl_xor(a, 16); a += __shfl_xor(a, 32);
        b += __shfl_xor(b, 16); b += __shfl_xor(b, 32);
        if (g == 0) {
            atomicAdd(&eStats[j], a);
            atomicAdd(&eStats[H + j], b);
        }
    }
}

// ---------------------------------------------------------------------------
// Node update, 512 threads: h = relu(bn_h(h)@V1 + aggmean@V2 + b2);
// fused h-stats; zeroes its aggsum rows.
__global__ __launch_bounds__(512, 4) void node_kernel(unsigned short* hb,
                                                      float* __restrict__ aggsum,
                                                      const short8* __restrict__ wfrL,
                                                      const float* __restrict__ b2, int M,
                                                      const float* __restrict__ Sh,
                                                      const float* __restrict__ gh,
                                                      const float* __restrict__ bh,
                                                      float invN,
                                                      float* __restrict__ hStats)
{
    __shared__ __align__(16) unsigned short sA[64 * 128];
    __shared__ __align__(16) unsigned short sB[64 * 128];
    __shared__ float bnp[256];
    const int t = threadIdx.x, lane = t & 63, w = t >> 6;
    const int r0 = blockIdx.x * 64;
    const int g = lane >> 4, c0 = lane & 15;
    const int j = 16 * w + c0;
    if (t < 128) bn_param(Sh, gh, bh, invN, t, bnp, bnp + 128);
    __syncthreads();
    stage_aff(hb, sA, r0, M, t, bnp, bnp + 128);
    stage_agg_bf16(aggsum, sB, r0, M, t);   // also zeroes consumed rows
    short8 wf[4];
    f32x4 acc[4];
    zero_acc_h(acc);
    load_wfrag_h(wfrL + 5 * 2048, w, lane, wf);   // V1
    __syncthreads();
    mfma_gemm_h(sA, wf, acc, lane);
    load_wfrag_h(wfrL + 6 * 2048, w, lane, wf);   // V2
    mfma_gemm_h(sB, wf, acc, lane);
    float s1 = 0.f, s2 = 0.f;
    {
        float bj = b2[j];
#pragma unroll
        for (int fr = 0; fr < 4; ++fr)
#pragma unroll
            for (int r = 0; r < 4; ++r) {
                int row = r0 + 16 * fr + 4 * g + r;
                if (row < M) {
                    float v = fmaxf(acc[fr][r] + bj, 0.f);
                    hb[(size_t)row * H + j] = f2bf(v);
                    s1 += v;
                    s2 += v * v;
                }
            }
    }
    {
        float a = s1, b = s2;
        a += __shfl_xor(a, 16); a += __shfl_xor(a, 32);
        b += __shfl_xor(b, 16); b += __shfl_xor(b, 32);
        if (g == 0) {
            atomicAdd(&hStats[j], a);
            atomicAdd(&hStats[H + j], b);
        }
    }
}

// ---------------------------------------------------------------------------
// Final readout: out = [mean(h) | mean(e)] @ reg_w + reg_b
__global__ __launch_bounds__(256) void final_kernel(const float* __restrict__ hsum,
                                                    const float* __restrict__ esum,
                                                    const float* __restrict__ reg_w,
                                                    const float* __restrict__ reg_b,
                                                    float* __restrict__ out,
                                                    float invN, float invE)
{
    __shared__ float red[256];
    int t = threadIdx.x;
    float v = (t < 128) ? hsum[t] * invN * reg_w[t]
                        : esum[t - 128] * invE * reg_w[t];
    red[t] = v;
    __syncthreads();
    for (int s = 128; s > 0; s >>= 1) {
        if (t < s) red[t] += red[t + s];
        __syncthreads();
    }
    if (t == 0) out[0] = red[0] + reg_b[0];
}

// ---------------------------------------------------------------------------
extern "C" void kernel_launch(void* const* d_in, const int* in_sizes, int n_in,
                              void* d_out, int out_size, void* d_ws, size_t ws_size,
                              hipStream_t stream)
{
    const float* x          = (const float*)d_in[0];
    const int*   edge_index = (const int*)  d_in[1];
    const float* edge_attr  = (const float*)d_in[2];
    const float* enc_node_w = (const float*)d_in[3];
    const float* enc_node_b = (const float*)d_in[4];
    const float* enc_edge_w = (const float*)d_in[5];
    const float* enc_edge_b = (const float*)d_in[6];
    const float* edge_w     = (const float*)d_in[7];
    const float* edge_b     = (const float*)d_in[8];
    const float* n1_w       = (const float*)d_in[9];
    const float* n1_b       = (const float*)d_in[10];
    const float* n2_w       = (const float*)d_in[11];
    const float* n2_b       = (const float*)d_in[12];
    const float* bn_node_g  = (const float*)d_in[13];
    const float* bn_node_b  = (const float*)d_in[14];
    const float* bn_edge_g  = (const float*)d_in[15];
    const float* bn_edge_b  = (const float*)d_in[16];
    const float* reg_w      = (const float*)d_in[17];
    const float* reg_b      = (const float*)d_in[18];

    const int N = in_sizes[0] / F_IN;
    const int E = in_sizes[1] / 2;
    const size_t NH = (size_t)N * H;
    const size_t EH = (size_t)E * H;

    float* ws     = (float*)d_ws;
    float* aggsum = ws;                 // [N,128] f32 (zeroed once; node re-zeroes)
    float* statsA = aggsum + NH;        // 512
    float* statsB = statsA + 512;       // 512
    short8* wfr   = (short8*)(statsB + 512);        // 21*2048 short8 = 672 KB
    unsigned short* hbuf = (unsigned short*)(wfr + 21 * 2048);  // [N,128] bf16
    unsigned short* ebuf = hbuf + NH;                           // [E,128] bf16 (col-sorted)
    int*   cnt_i  = (int*)(ebuf + EH);      // [N]
    int*   tmpc   = cnt_i + N;              // [N]
    int*   offs   = tmpc + N;               // [N+1]
    int*   sortedIds = offs + N + 1;        // [E]
    int*   rowS   = sortedIds + E;          // [E]
    int*   colS   = rowS + E;               // [E]

    const int* row_idx = edge_index;
    const int* col_idx = edge_index + E;
    const float invN = 1.f / (float)N;
    const float invE = 1.f / (float)E;

    // one-time: sort edges by col; bf16 weight fragments; encoders
    (void)hipMemsetAsync(cnt_i, 0, (size_t)2 * N * sizeof(int), stream);
    (void)hipMemsetAsync(aggsum, 0, NH * sizeof(float), stream);
    hist_kernel<<<(E + 255) / 256, 256, 0, stream>>>(col_idx, cnt_i, E);
    scan_kernel<<<1, 1024, 0, stream>>>(cnt_i, offs, N);
    scatter_kernel<<<(E + 255) / 256, 256, 0, stream>>>(row_idx, col_idx, offs, tmpc,
                                                        sortedIds, rowS, colS, E);
    wbf16_kernel<<<21, 256, 0, stream>>>(edge_w, n1_w, n2_w, wfr);

    enc_kernel<<<(N + 1) / 2, 256, 0, stream>>>(x, enc_node_w, enc_node_b, hbuf, N);
    enc_gather_kernel<<<(E + 1) / 2, 256, 0, stream>>>(edge_attr, sortedIds,
                                                       enc_edge_w, enc_edge_b, ebuf, E);

    const int nodeBlocks = (N + 63) / 64;
    const int edgeBlocks = (E + 63) / 64;

    for (int i = 0; i < 3; ++i) {
        float*       Scur  = (i & 1) ? statsB : statsA;
        const float* Sprev = (i == 0) ? nullptr : ((i & 1) ? statsA : statsB);
        const float* Sh = Sprev;
        const float* Se = Sprev ? Sprev + 256 : nullptr;
        const short8* wfrL = wfr + (size_t)i * 7 * 2048;
        (void)hipMemsetAsync(Scur, 0, 512 * sizeof(float), stream);
        edge_kernel<<<edgeBlocks, 512, 0, stream>>>(
            ebuf, rowS, colS, cnt_i, hbuf, wfrL,
            edge_b + i * H, n1_b + i * H,
            aggsum, E,
            Sh, bn_node_g, bn_node_b, invN,
            Se, bn_edge_g, bn_edge_b, invE,
            Scur + 256);
        node_kernel<<<nodeBlocks, 512, 0, stream>>>(
            hbuf, aggsum, wfrL, n2_b + i * H, N,
            Sh, bn_node_g, bn_node_b, invN,
            Scur);
    }
    // i=2 wrote statsA
    final_kernel<<<1, 256, 0, stream>>>(statsA, statsA + 256, reg_w, reg_b,
                                        (float*)d_out, invN, invE);
}

// Round 22
// 738.782 us; speedup vs baseline: 1.0751x; 1.0751x over previous
//
#include <hip/hip_runtime.h>

#define H 128
#define F_IN 16
#define BNEPS 1e-5f

typedef __attribute__((ext_vector_type(8))) short short8;
typedef __attribute__((ext_vector_type(4))) float f32x4;

// f32 -> bf16 round-to-nearest-even
__device__ __forceinline__ unsigned short f2bf(float f)
{
    unsigned u = __builtin_bit_cast(unsigned, f);
    u += 0x7FFFu + ((u >> 16) & 1u);
    return (unsigned short)(u >> 16);
}
__device__ __forceinline__ float bf2f(unsigned short h)
{
    return __builtin_bit_cast(float, (unsigned)h << 16);
}

// BN affine params for feature j: s[j], t[j] (identity if S==nullptr)
__device__ __forceinline__ void bn_param(const float* __restrict__ S,
                                         const float* __restrict__ g,
                                         const float* __restrict__ b,
                                         float invM, int j,
                                         float* __restrict__ sS, float* __restrict__ sT)
{
    float s = 1.f, tt = 0.f;
    if (S) {
        float mean = S[j] * invM;
        float var  = S[H + j] * invM - mean * mean;
        s  = rsqrtf(var + BNEPS) * g[j];
        tt = b[j] - mean * s;
    }
    sS[j] = s;
    sT[j] = tt;
}

// ---------------------------------------------------------------------------
// 512-thread staging: 64x128 bf16 tile with per-feature affine into swizzled
// LDS. element (row,k) -> ushort idx row*128 + (k ^ ((row&7)<<3))
__device__ __forceinline__ void stage_aff(const unsigned short* __restrict__ src,
                                          unsigned short* sA, int r0, int M, int t,
                                          const float* __restrict__ sS,
                                          const float* __restrict__ sT)
{
#pragma unroll
    for (int i = 0; i < 2; ++i) {
        int cid  = t + 512 * i;
        int row  = cid >> 4;
        int ck   = cid & 15;
        int grow = r0 + row;
        short8 v = (short8)0;
        if (grow < M) {
            v = *(const short8*)(src + (size_t)grow * H + ck * 8);
            int j0 = ck * 8;
#pragma unroll
            for (int j = 0; j < 8; ++j)
                v[j] = (short)f2bf(bf2f((unsigned short)v[j]) * sS[j0 + j] + sT[j0 + j]);
        }
        *(short8*)(sA + (row << 7) + ((ck ^ (row & 7)) << 3)) = v;
    }
}

// Gather variant: tile row i holds src[idx[p0+i]], same affine.
__device__ __forceinline__ void stage_aff_gather(const unsigned short* __restrict__ src,
                                                 const int* __restrict__ idx,
                                                 unsigned short* sA, int p0, int M, int t,
                                                 const float* __restrict__ sS,
                                                 const float* __restrict__ sT)
{
#pragma unroll
    for (int i = 0; i < 2; ++i) {
        int cid = t + 512 * i;
        int row = cid >> 4;
        int ck  = cid & 15;
        int p   = p0 + row;
        short8 v = (short8)0;
        if (p < M) {
            v = *(const short8*)(src + (size_t)idx[p] * H + ck * 8);
            int j0 = ck * 8;
#pragma unroll
            for (int j = 0; j < 8; ++j)
                v[j] = (short)f2bf(bf2f((unsigned short)v[j]) * sS[j0 + j] + sT[j0 + j]);
        }
        *(short8*)(sA + (row << 7) + ((ck ^ (row & 7)) << 3)) = v;
    }
}

// aggsum holds per-node MEANS -> convert to bf16; then zero rows for next layer
__device__ __forceinline__ void stage_agg_bf16(float* __restrict__ aggsum,
                                               unsigned short* sA, int r0, int M, int t)
{
#pragma unroll
    for (int i = 0; i < 2; ++i) {
        int cid  = t + 512 * i;
        int row  = cid >> 4;
        int ck   = cid & 15;
        int grow = r0 + row;
        short8 ph = (short8)0;
        if (grow < M) {
            float4* q = (float4*)(aggsum + (size_t)grow * H + ck * 8);
            float4 a = q[0], b = q[1];
            float xs[8] = {a.x, a.y, a.z, a.w, b.x, b.y, b.z, b.w};
#pragma unroll
            for (int j = 0; j < 8; ++j) ph[j] = (short)f2bf(xs[j]);
            q[0] = make_float4(0.f, 0.f, 0.f, 0.f);
            q[1] = make_float4(0.f, 0.f, 0.f, 0.f);
        }
        *(short8*)(sA + (row << 7) + ((ck ^ (row & 7)) << 3)) = ph;
    }
}

// ---------------------------------------------------------------------------
// One-time weight bf16 fragment precompute (21 matrices, unscaled).
__global__ __launch_bounds__(256) void wbf16_kernel(const float* __restrict__ edge_w,
                                                    const float* __restrict__ n1_w,
                                                    const float* __restrict__ n2_w,
                                                    short8* __restrict__ out)
{
    int m = blockIdx.x;
    int layer = m / 7, k = m % 7;
    const float* W = (k < 3) ? edge_w + (size_t)layer * 384 * H + (size_t)k * H * H
                   : (k < 5) ? n1_w + (size_t)layer * 256 * H + (size_t)(k - 3) * H * H
                             : n2_w + (size_t)layer * 256 * H + (size_t)(k - 5) * H * H;
    short8* oh = out + (size_t)m * 2048;
    for (int e = threadIdx.x; e < 2048; e += 256) {
        int jbB = e >> 9, s = (e >> 7) & 3, c = (e >> 6) & 1, lane = e & 63;
        int g = lane >> 4, c0 = lane & 15;
        short8 hi;
#pragma unroll
        for (int j = 0; j < 8; ++j)
            hi[j] = (short)f2bf(W[(size_t)(32 * s + 8 * g + j) * H + jbB * 32 + 16 * c + c0]);
        oh[e] = hi;
    }
}

// Wave w (0..7) owns cols [16w,16w+16): fragment idx jbB=w>>1, cB=w&1.
__device__ __forceinline__ void load_wfrag_h(const short8* __restrict__ Wp, int w,
                                             int lane, short8 wf[4])
{
    int base = ((w >> 1) * 8 + (w & 1)) * 64 + lane;
#pragma unroll
    for (int s = 0; s < 4; ++s)
        wf[s] = Wp[base + s * 128];
}

// acc[fr] += sA(64x128 bf16, swizzled) @ Wf(128x16 bf16)   (16 MFMA)
__device__ __forceinline__ void mfma_gemm_h(const unsigned short* sA, const short8 wf[4],
                                            f32x4 acc[4], int lane)
{
    const int g = lane >> 4, r = lane & 15;
#pragma unroll
    for (int s = 0; s < 4; ++s) {
        short8 a4[4];
#pragma unroll
        for (int fr = 0; fr < 4; ++fr) {
            int row = 16 * fr + r;
            int ck  = (4 * s + g) ^ (row & 7);
            a4[fr] = *(const short8*)(sA + (row << 7) + (ck << 3));
        }
#pragma unroll
        for (int fr = 0; fr < 4; ++fr)
            acc[fr] = __builtin_amdgcn_mfma_f32_16x16x32_bf16(a4[fr], wf[s], acc[fr], 0, 0, 0);
    }
}

__device__ __forceinline__ void zero_acc_h(f32x4 acc[4])
{
#pragma unroll
    for (int fr = 0; fr < 4; ++fr) {
        acc[fr][0] = 0.f; acc[fr][1] = 0.f; acc[fr][2] = 0.f; acc[fr][3] = 0.f;
    }
}

// ---------------------------------------------------------------------------
// One-time sort machinery (edge_index is layer-invariant)
__global__ __launch_bounds__(256) void hist_kernel(const int* __restrict__ col,
                                                   int* __restrict__ cnt, int E)
{
    int e = blockIdx.x * 256 + threadIdx.x;
    if (e < E) atomicAdd(&cnt[col[e]], 1);
}

__global__ __launch_bounds__(1024) void scan_kernel(const int* __restrict__ cnt,
                                                    int* __restrict__ offs, int Nn)
{
    __shared__ int ls[1024];
    int t = threadIdx.x;
    int per = (Nn + 1023) / 1024;
    int base = t * per;
    int s = 0;
    for (int k = 0; k < per; ++k) {
        int i = base + k;
        if (i < Nn) s += cnt[i];
    }
    ls[t] = s;
    __syncthreads();
    for (int d = 1; d < 1024; d <<= 1) {
        int u = (t >= d) ? ls[t - d] : 0;
        __syncthreads();
        ls[t] += u;
        __syncthreads();
    }
    int run = ls[t] - s;
    for (int k = 0; k < per; ++k) {
        int i = base + k;
        if (i < Nn) {
            offs[i] = run;
            run += cnt[i];
        }
    }
}

__global__ __launch_bounds__(256) void scatter_kernel(const int* __restrict__ row,
                                                      const int* __restrict__ col,
                                                      const int* __restrict__ offs,
                                                      int* __restrict__ tmpc,
                                                      int* __restrict__ sortedIds,
                                                      int* __restrict__ rowS,
                                                      int* __restrict__ colS, int E)
{
    int e = blockIdx.x * 256 + threadIdx.x;
    if (e < E) {
        int c = col[e];
        int p = offs[c] + atomicAdd(&tmpc[c], 1);
        sortedIds[p] = e;
        rowS[p] = row[e];
        colS[p] = c;
    }
}

// ---------------------------------------------------------------------------
// Encoder: out(bf16) = relu(X[M,16] @ W[16,128] + b)
__global__ __launch_bounds__(256) void enc_kernel(const float* __restrict__ X,
                                                  const float* __restrict__ W,
                                                  const float* __restrict__ bias,
                                                  unsigned short* __restrict__ out, int M)
{
    __shared__ float sW[F_IN * H];
    __shared__ float sb[H];
    int t = threadIdx.x;
    reinterpret_cast<float4*>(sW)[t]       = reinterpret_cast<const float4*>(W)[t];
    reinterpret_cast<float4*>(sW)[t + 256] = reinterpret_cast<const float4*>(W)[t + 256];
    if (t < H) sb[t] = bias[t];
    __syncthreads();
    int row = blockIdx.x * 2 + (t >> 7);
    if (row >= M) return;
    int j = t & 127;
    float acc = sb[j];
#pragma unroll
    for (int k = 0; k < F_IN; ++k)
        acc += X[(size_t)row * F_IN + k] * sW[k * H + j];
    out[(size_t)row * H + j] = f2bf(fmaxf(acc, 0.f));
}

// Gather-encoder: out[p](bf16) = relu(X[sortedIds[p],16] @ W + b)
__global__ __launch_bounds__(256) void enc_gather_kernel(const float* __restrict__ X,
                                                         const int* __restrict__ sortedIds,
                                                         const float* __restrict__ W,
                                                         const float* __restrict__ bias,
                                                         unsigned short* __restrict__ out,
                                                         int M)
{
    __shared__ float sW[F_IN * H];
    __shared__ float sb[H];
    int t = threadIdx.x;
    reinterpret_cast<float4*>(sW)[t]       = reinterpret_cast<const float4*>(W)[t];
    reinterpret_cast<float4*>(sW)[t + 256] = reinterpret_cast<const float4*>(W)[t + 256];
    if (t < H) sb[t] = bias[t];
    __syncthreads();
    int p = blockIdx.x * 2 + (t >> 7);
    if (p >= M) return;
    int src = sortedIds[p];
    int j = t & 127;
    float acc = sb[j];
#pragma unroll
    for (int k = 0; k < F_IN; ++k)
        acc += X[(size_t)src * F_IN + k] * sW[k * H + j];
    out[(size_t)p * H + j] = f2bf(fmaxf(acc, 0.f));
}

// ---------------------------------------------------------------------------
// Fused edge kernel, 512 threads (8 waves x 16-col strips):
//   e'[p] = relu(bn_e(e[p])@W3 + bn_h(h[rowS])@W1 + bn_h(h[colS])@W2 + be)
//   m     = relu(e'@U2 + bn_h(h[rowS])@U1 + b1)
//   aggsum[col] += segment-MEAN partials (mbuf, 4-way) ; fused e'-stats
//   e' written to global via coalesced LDS stage-out.
__global__ __launch_bounds__(512, 3) void edge_kernel(unsigned short* eb,
                                                      const int* __restrict__ rowS,
                                                      const int* __restrict__ colS,
                                                      const int* __restrict__ cnt,
                                                      const unsigned short* __restrict__ hb,
                                                      const short8* __restrict__ wfrL,
                                                      const float* __restrict__ be,
                                                      const float* __restrict__ b1,
                                                      float* __restrict__ aggsum, int E,
                                                      const float* __restrict__ Sh,
                                                      const float* __restrict__ gh,
                                                      const float* __restrict__ bh,
                                                      float invN,
                                                      const float* __restrict__ Se,
                                                      const float* __restrict__ ge,
                                                      const float* __restrict__ beB,
                                                      float invE,
                                                      float* __restrict__ eStats)
{
    __shared__ __align__(16) unsigned char smem[64 * 128 * 6 + 256 + 256 + 2048];
    unsigned short* sE  = (unsigned short*)smem;          // 16 KB  e (bf16)
    unsigned short* sHt = sE + 64 * 128;                  // 16 KB  h[rowS] (bf16)
    unsigned short* sHc = sHt + 64 * 128;                 // 16 KB  h[colS] (bf16)
    float*          mbuf = (float*)smem;                  // 32 KB overlay sE+sHt
    int*            scol = (int*)(smem + 64 * 128 * 6);          // 256 B
    float*          sinv = (float*)(smem + 64 * 128 * 6 + 256);  // 256 B
    float*          bnp  = (float*)(smem + 64 * 128 * 6 + 512);  // 2 KB

    const int t = threadIdx.x, lane = t & 63, w = t >> 6;
    const int e0 = blockIdx.x * 64;
    const int g = lane >> 4, c0 = lane & 15;
    const int j = 16 * w + c0;        // this lane's output column

    if (t < 64) {
        int cc = colS[(e0 + t < E) ? (e0 + t) : (E - 1)];
        scol[t] = cc;
        int c = cnt[cc];
        sinv[t] = 1.f / (float)(c > 1 ? c : 1);
    }
    if (t >= 64 && t < 192)      bn_param(Sh, gh, bh, invN, t - 64, bnp, bnp + 128);
    else if (t >= 192 && t < 320) bn_param(Se, ge, beB, invE, t - 192, bnp + 256, bnp + 384);
    __syncthreads();   // bnp + scol ready

    stage_aff(eb, sE, e0, E, t, bnp + 256, bnp + 384);
    stage_aff_gather(hb, rowS, sHt, e0, E, t, bnp, bnp + 128);
    {
        int Mt = E - e0; if (Mt > 64) Mt = 64;
        stage_aff_gather(hb, scol, sHc, 0, Mt, t, bnp, bnp + 128);
    }

    short8 wf[4];
    f32x4 acc[4];
    zero_acc_h(acc);
    load_wfrag_h(wfrL + 2 * 2048, w, lane, wf);   // W3
    __syncthreads();
    mfma_gemm_h(sE, wf, acc, lane);
    load_wfrag_h(wfrL + 0 * 2048, w, lane, wf);   // W1
    mfma_gemm_h(sHt, wf, acc, lane);
    load_wfrag_h(wfrL + 1 * 2048, w, lane, wf);   // W2 (B-term)
    mfma_gemm_h(sHc, wf, acc, lane);
    __syncthreads();   // all reads of sE done -> safe to overwrite with e'

    // epilogue 1: e' = relu(acc + be) -> sE (swizzled) + stats in registers
    float s1 = 0.f, s2 = 0.f;
    {
        float bej = be[j];
#pragma unroll
        for (int fr = 0; fr < 4; ++fr)
#pragma unroll
            for (int r = 0; r < 4; ++r) {
                int Rl = 16 * fr + 4 * g + r;
                int p  = e0 + Rl;
                float v = acc[fr][r] + bej;
                v = fmaxf(v, 0.f);
                unsigned short vb = f2bf(v);
                if (p < E) {
                    s1 += v;
                    s2 += v * v;
                }
                sE[(Rl << 7) + (j ^ ((Rl & 7) << 3))] = vb;
            }
    }
    __syncthreads();   // sE complete

    // coalesced e' stage-out: 2 x 16B stores per thread (reads sE, unswizzled)
#pragma unroll
    for (int i = 0; i < 2; ++i) {
        int cid = t + 512 * i;
        int row = cid >> 4;
        int ck  = cid & 15;
        int p   = e0 + row;
        if (p < E) {
            short8 v = *(const short8*)(sE + (row << 7) + ((ck ^ (row & 7)) << 3));
            *(short8*)(eb + (size_t)p * H + ck * 8) = v;
        }
    }

    // GEMM2: m = e'@U2 + bn_h(h[rowS])@U1
    zero_acc_h(acc);
    load_wfrag_h(wfrL + 4 * 2048, w, lane, wf);   // U2
    mfma_gemm_h(sE, wf, acc, lane);
    load_wfrag_h(wfrL + 3 * 2048, w, lane, wf);   // U1
    mfma_gemm_h(sHt, wf, acc, lane);
    __syncthreads();   // all GEMM2 LDS reads done -> mbuf overlay safe

    // epilogue 2: m -> mbuf (swizzled)
    {
        float b1j = b1[j];
#pragma unroll
        for (int fr = 0; fr < 4; ++fr)
#pragma unroll
            for (int r = 0; r < 4; ++r) {
                int Rl = 16 * fr + 4 * g + r;
                float v = fmaxf(acc[fr][r] + b1j, 0.f);
                mbuf[(Rl << 7) + (j ^ (((Rl >> 2) & 3) << 3))] = v;
            }
    }
    __syncthreads();

    // segmented reduction, 4-way parallel over row quarters (512 threads)
    {
        int jc = t & 127, q = t >> 7;
        int rbeg = q * 16, rend = rbeg + 16;
        int rlim = E - e0;
        float run = 0.f;
        int cur = scol[rbeg];
        for (int row = rbeg; row < rend; ++row) {
            int cc = scol[row];
            float v = mbuf[(row << 7) + (jc ^ (((row >> 2) & 3) << 3))];
            if (cc != cur) {
                if (run != 0.f)
                    atomicAdd(&aggsum[(size_t)cur * H + jc], run * sinv[row - 1]);
                run = 0.f;
                cur = cc;
            }
            if (row < rlim) run += v;
        }
        if (run != 0.f)
            atomicAdd(&aggsum[(size_t)cur * H + jc], run * sinv[rend - 1]);
    }

    // fused e'-stats
    {
        float a = s1, b = s2;
        a += __shfl_xor(a, 16); a += __shfl_xor(a, 32);
        b += __shfl_xor(b, 16); b += __shfl_xor(b, 32);
        if (g == 0) {
            atomicAdd(&eStats[j], a);
            atomicAdd(&eStats[H + j], b);
        }
    }
}

// ---------------------------------------------------------------------------
// Node update, 512 threads: h = relu(bn_h(h)@V1 + aggmean@V2 + b2);
// fused h-stats; zeroes its aggsum rows.
__global__ __launch_bounds__(512, 4) void node_kernel(unsigned short* hb,
                                                      float* __restrict__ aggsum,
                                                      const short8* __restrict__ wfrL,
                                                      const float* __restrict__ b2, int M,
                                                      const float* __restrict__ Sh,
                                                      const float* __restrict__ gh,
                                                      const float* __restrict__ bh,
                                                      float invN,
                                                      float* __restrict__ hStats)
{
    __shared__ __align__(16) unsigned short sA[64 * 128];
    __shared__ __align__(16) unsigned short sB[64 * 128];
    __shared__ float bnp[256];
    const int t = threadIdx.x, lane = t & 63, w = t >> 6;
    const int r0 = blockIdx.x * 64;
    const int g = lane >> 4, c0 = lane & 15;
    const int j = 16 * w + c0;
    if (t < 128) bn_param(Sh, gh, bh, invN, t, bnp, bnp + 128);
    __syncthreads();
    stage_aff(hb, sA, r0, M, t, bnp, bnp + 128);
    stage_agg_bf16(aggsum, sB, r0, M, t);   // also zeroes consumed rows
    short8 wf[4];
    f32x4 acc[4];
    zero_acc_h(acc);
    load_wfrag_h(wfrL + 5 * 2048, w, lane, wf);   // V1
    __syncthreads();
    mfma_gemm_h(sA, wf, acc, lane);
    load_wfrag_h(wfrL + 6 * 2048, w, lane, wf);   // V2
    mfma_gemm_h(sB, wf, acc, lane);
    float s1 = 0.f, s2 = 0.f;
    {
        float bj = b2[j];
#pragma unroll
        for (int fr = 0; fr < 4; ++fr)
#pragma unroll
            for (int r = 0; r < 4; ++r) {
                int row = r0 + 16 * fr + 4 * g + r;
                if (row < M) {
                    float v = fmaxf(acc[fr][r] + bj, 0.f);
                    hb[(size_t)row * H + j] = f2bf(v);
                    s1 += v;
                    s2 += v * v;
                }
            }
    }
    {
        float a = s1, b = s2;
        a += __shfl_xor(a, 16); a += __shfl_xor(a, 32);
        b += __shfl_xor(b, 16); b += __shfl_xor(b, 32);
        if (g == 0) {
            atomicAdd(&hStats[j], a);
            atomicAdd(&hStats[H + j], b);
        }
    }
}

// ---------------------------------------------------------------------------
// Final readout: out = [mean(h) | mean(e)] @ reg_w + reg_b
__global__ __launch_bounds__(256) void final_kernel(const float* __restrict__ hsum,
                                                    const float* __restrict__ esum,
                                                    const float* __restrict__ reg_w,
                                                    const float* __restrict__ reg_b,
                                                    float* __restrict__ out,
                                                    float invN, float invE)
{
    __shared__ float red[256];
    int t = threadIdx.x;
    float v = (t < 128) ? hsum[t] * invN * reg_w[t]
                        : esum[t - 128] * invE * reg_w[t];
    red[t] = v;
    __syncthreads();
    for (int s = 128; s > 0; s >>= 1) {
        if (t < s) red[t] += red[t + s];
        __syncthreads();
    }
    if (t == 0) out[0] = red[0] + reg_b[0];
}

// ---------------------------------------------------------------------------
extern "C" void kernel_launch(void* const* d_in, const int* in_sizes, int n_in,
                              void* d_out, int out_size, void* d_ws, size_t ws_size,
                              hipStream_t stream)
{
    const float* x          = (const float*)d_in[0];
    const int*   edge_index = (const int*)  d_in[1];
    const float* edge_attr  = (const float*)d_in[2];
    const float* enc_node_w = (const float*)d_in[3];
    const float* enc_node_b = (const float*)d_in[4];
    const float* enc_edge_w = (const float*)d_in[5];
    const float* enc_edge_b = (const float*)d_in[6];
    const float* edge_w     = (const float*)d_in[7];
    const float* edge_b     = (const float*)d_in[8];
    const float* n1_w       = (const float*)d_in[9];
    const float* n1_b       = (const float*)d_in[10];
    const float* n2_w       = (const float*)d_in[11];
    const float* n2_b       = (const float*)d_in[12];
    const float* bn_node_g  = (const float*)d_in[13];
    const float* bn_node_b  = (const float*)d_in[14];
    const float* bn_edge_g  = (const float*)d_in[15];
    const float* bn_edge_b  = (const float*)d_in[16];
    const float* reg_w      = (const float*)d_in[17];
    const float* reg_b      = (const float*)d_in[18];

    const int N = in_sizes[0] / F_IN;
    const int E = in_sizes[1] / 2;
    const size_t NH = (size_t)N * H;
    const size_t EH = (size_t)E * H;

    float* ws     = (float*)d_ws;
    float* aggsum = ws;                 // [N,128] f32 (zeroed once; node re-zeroes)
    float* statsA = aggsum + NH;        // 512
    float* statsB = statsA + 512;       // 512
    short8* wfr   = (short8*)(statsB + 512);        // 21*2048 short8 = 672 KB
    unsigned short* hbuf = (unsigned short*)(wfr + 21 * 2048);  // [N,128] bf16
    unsigned short* ebuf = hbuf + NH;                           // [E,128] bf16 (col-sorted)
    int*   cnt_i  = (int*)(ebuf + EH);      // [N]
    int*   tmpc   = cnt_i + N;              // [N]
    int*   offs   = tmpc + N;               // [N+1]
    int*   sortedIds = offs + N + 1;        // [E]
    int*   rowS   = sortedIds + E;          // [E]
    int*   colS   = rowS + E;               // [E]

    const int* row_idx = edge_index;
    const int* col_idx = edge_index + E;
    const float invN = 1.f / (float)N;
    const float invE = 1.f / (float)E;

    // one-time: sort edges by col; bf16 weight fragments; encoders
    (void)hipMemsetAsync(cnt_i, 0, (size_t)2 * N * sizeof(int), stream);
    (void)hipMemsetAsync(aggsum, 0, NH * sizeof(float), stream);
    hist_kernel<<<(E + 255) / 256, 256, 0, stream>>>(col_idx, cnt_i, E);
    scan_kernel<<<1, 1024, 0, stream>>>(cnt_i, offs, N);
    scatter_kernel<<<(E + 255) / 256, 256, 0, stream>>>(row_idx, col_idx, offs, tmpc,
                                                        sortedIds, rowS, colS, E);
    wbf16_kernel<<<21, 256, 0, stream>>>(edge_w, n1_w, n2_w, wfr);

    enc_kernel<<<(N + 1) / 2, 256, 0, stream>>>(x, enc_node_w, enc_node_b, hbuf, N);
    enc_gather_kernel<<<(E + 1) / 2, 256, 0, stream>>>(edge_attr, sortedIds,
                                                       enc_edge_w, enc_edge_b, ebuf, E);

    const int nodeBlocks = (N + 63) / 64;
    const int edgeBlocks = (E + 63) / 64;

    for (int i = 0; i < 3; ++i) {
        float*       Scur  = (i & 1) ? statsB : statsA;
        const float* Sprev = (i == 0) ? nullptr : ((i & 1) ? statsA : statsB);
        const float* Sh = Sprev;
        const float* Se = Sprev ? Sprev + 256 : nullptr;
        const short8* wfrL = wfr + (size_t)i * 7 * 2048;
        (void)hipMemsetAsync(Scur, 0, 512 * sizeof(float), stream);
        edge_kernel<<<edgeBlocks, 512, 0, stream>>>(
            ebuf, rowS, colS, cnt_i, hbuf, wfrL,
            edge_b + i * H, n1_b + i * H,
            aggsum, E,
            Sh, bn_node_g, bn_node_b, invN,
            Se, bn_edge_g, bn_edge_b, invE,
            Scur + 256);
        node_kernel<<<nodeBlocks, 512, 0, stream>>>(
            hbuf, aggsum, wfrL, n2_b + i * H, N,
            Sh, bn_node_g, bn_node_b, invN,
            Scur);
    }
    // i=2 wrote statsA
    final_kernel<<<1, 256, 0, stream>>>(statsA, statsA + 256, reg_w, reg_b,
                                        (float*)d_out, invN, invE);
}

// Round 23
// 738.063 us; speedup vs baseline: 1.0762x; 1.0010x over previous
//
#include <hip/hip_runtime.h>

#define H 128
#define F_IN 16
#define BNEPS 1e-5f

typedef __attribute__((ext_vector_type(8))) short short8;
typedef __attribute__((ext_vector_type(4))) float f32x4;

// f32 -> bf16 round-to-nearest-even
__device__ __forceinline__ unsigned short f2bf(float f)
{
    unsigned u = __builtin_bit_cast(unsigned, f);
    u += 0x7FFFu + ((u >> 16) & 1u);
    return (unsigned short)(u >> 16);
}
__device__ __forceinline__ float bf2f(unsigned short h)
{
    return __builtin_bit_cast(float, (unsigned)h << 16);
}

// BN affine params for feature j: s[j], t[j] (identity if S==nullptr)
__device__ __forceinline__ void bn_param(const float* __restrict__ S,
                                         const float* __restrict__ g,
                                         const float* __restrict__ b,
                                         float invM, int j,
                                         float* __restrict__ sS, float* __restrict__ sT)
{
    float s = 1.f, tt = 0.f;
    if (S) {
        float mean = S[j] * invM;
        float var  = S[H + j] * invM - mean * mean;
        s  = rsqrtf(var + BNEPS) * g[j];
        tt = b[j] - mean * s;
    }
    sS[j] = s;
    sT[j] = tt;
}

// ---------------------------------------------------------------------------
// 512-thread staging: 64x128 bf16 tile with per-feature affine into swizzled
// LDS. element (row,k) -> ushort idx row*128 + (k ^ ((row&7)<<3))
__device__ __forceinline__ void stage_aff(const unsigned short* __restrict__ src,
                                          unsigned short* sA, int r0, int M, int t,
                                          const float* __restrict__ sS,
                                          const float* __restrict__ sT)
{
#pragma unroll
    for (int i = 0; i < 2; ++i) {
        int cid  = t + 512 * i;
        int row  = cid >> 4;
        int ck   = cid & 15;
        int grow = r0 + row;
        short8 v = (short8)0;
        if (grow < M) {
            v = *(const short8*)(src + (size_t)grow * H + ck * 8);
            int j0 = ck * 8;
#pragma unroll
            for (int j = 0; j < 8; ++j)
                v[j] = (short)f2bf(bf2f((unsigned short)v[j]) * sS[j0 + j] + sT[j0 + j]);
        }
        *(short8*)(sA + (row << 7) + ((ck ^ (row & 7)) << 3)) = v;
    }
}

// Gather variant: tile row i holds src[idx[p0+i]], same affine.
__device__ __forceinline__ void stage_aff_gather(const unsigned short* __restrict__ src,
                                                 const int* __restrict__ idx,
                                                 unsigned short* sA, int p0, int M, int t,
                                                 const float* __restrict__ sS,
                                                 const float* __restrict__ sT)
{
#pragma unroll
    for (int i = 0; i < 2; ++i) {
        int cid = t + 512 * i;
        int row = cid >> 4;
        int ck  = cid & 15;
        int p   = p0 + row;
        short8 v = (short8)0;
        if (p < M) {
            v = *(const short8*)(src + (size_t)idx[p] * H + ck * 8);
            int j0 = ck * 8;
#pragma unroll
            for (int j = 0; j < 8; ++j)
                v[j] = (short)f2bf(bf2f((unsigned short)v[j]) * sS[j0 + j] + sT[j0 + j]);
        }
        *(short8*)(sA + (row << 7) + ((ck ^ (row & 7)) << 3)) = v;
    }
}

// aggsum holds per-node MEANS -> convert to bf16; then zero rows for next layer
__device__ __forceinline__ void stage_agg_bf16(float* __restrict__ aggsum,
                                               unsigned short* sA, int r0, int M, int t)
{
#pragma unroll
    for (int i = 0; i < 2; ++i) {
        int cid  = t + 512 * i;
        int row  = cid >> 4;
        int ck   = cid & 15;
        int grow = r0 + row;
        short8 ph = (short8)0;
        if (grow < M) {
            float4* q = (float4*)(aggsum + (size_t)grow * H + ck * 8);
            float4 a = q[0], b = q[1];
            float xs[8] = {a.x, a.y, a.z, a.w, b.x, b.y, b.z, b.w};
#pragma unroll
            for (int j = 0; j < 8; ++j) ph[j] = (short)f2bf(xs[j]);
            q[0] = make_float4(0.f, 0.f, 0.f, 0.f);
            q[1] = make_float4(0.f, 0.f, 0.f, 0.f);
        }
        *(short8*)(sA + (row << 7) + ((ck ^ (row & 7)) << 3)) = ph;
    }
}

// ---------------------------------------------------------------------------
// One-time weight bf16 fragment precompute (21 matrices, unscaled).
__global__ __launch_bounds__(256) void wbf16_kernel(const float* __restrict__ edge_w,
                                                    const float* __restrict__ n1_w,
                                                    const float* __restrict__ n2_w,
                                                    short8* __restrict__ out)
{
    int m = blockIdx.x;
    int layer = m / 7, k = m % 7;
    const float* W = (k < 3) ? edge_w + (size_t)layer * 384 * H + (size_t)k * H * H
                   : (k < 5) ? n1_w + (size_t)layer * 256 * H + (size_t)(k - 3) * H * H
                             : n2_w + (size_t)layer * 256 * H + (size_t)(k - 5) * H * H;
    short8* oh = out + (size_t)m * 2048;
    for (int e = threadIdx.x; e < 2048; e += 256) {
        int jbB = e >> 9, s = (e >> 7) & 3, c = (e >> 6) & 1, lane = e & 63;
        int g = lane >> 4, c0 = lane & 15;
        short8 hi;
#pragma unroll
        for (int j = 0; j < 8; ++j)
            hi[j] = (short)f2bf(W[(size_t)(32 * s + 8 * g + j) * H + jbB * 32 + 16 * c + c0]);
        oh[e] = hi;
    }
}

// Wave w (0..7) owns cols [16w,16w+16): fragment idx jbB=w>>1, cB=w&1.
__device__ __forceinline__ void load_wfrag_h(const short8* __restrict__ Wp, int w,
                                             int lane, short8 wf[4])
{
    int base = ((w >> 1) * 8 + (w & 1)) * 64 + lane;
#pragma unroll
    for (int s = 0; s < 4; ++s)
        wf[s] = Wp[base + s * 128];
}

// acc[fr] += sA(64x128 bf16, swizzled) @ Wf(128x16 bf16)   (16 MFMA)
__device__ __forceinline__ void mfma_gemm_h(const unsigned short* sA, const short8 wf[4],
                                            f32x4 acc[4], int lane)
{
    const int g = lane >> 4, r = lane & 15;
#pragma unroll
    for (int s = 0; s < 4; ++s) {
        short8 a4[4];
#pragma unroll
        for (int fr = 0; fr < 4; ++fr) {
            int row = 16 * fr + r;
            int ck  = (4 * s + g) ^ (row & 7);
            a4[fr] = *(const short8*)(sA + (row << 7) + (ck << 3));
        }
#pragma unroll
        for (int fr = 0; fr < 4; ++fr)
            acc[fr] = __builtin_amdgcn_mfma_f32_16x16x32_bf16(a4[fr], wf[s], acc[fr], 0, 0, 0);
    }
}

__device__ __forceinline__ void zero_acc_h(f32x4 acc[4])
{
#pragma unroll
    for (int fr = 0; fr < 4; ++fr) {
        acc[fr][0] = 0.f; acc[fr][1] = 0.f; acc[fr][2] = 0.f; acc[fr][3] = 0.f;
    }
}

// ---------------------------------------------------------------------------
// One-time sort machinery (edge_index is layer-invariant)
__global__ __launch_bounds__(256) void hist_kernel(const int* __restrict__ col,
                                                   int* __restrict__ cnt, int E)
{
    int e = blockIdx.x * 256 + threadIdx.x;
    if (e < E) atomicAdd(&cnt[col[e]], 1);
}

__global__ __launch_bounds__(1024) void scan_kernel(const int* __restrict__ cnt,
                                                    int* __restrict__ offs, int Nn)
{
    __shared__ int ls[1024];
    int t = threadIdx.x;
    int per = (Nn + 1023) / 1024;
    int base = t * per;
    int s = 0;
    for (int k = 0; k < per; ++k) {
        int i = base + k;
        if (i < Nn) s += cnt[i];
    }
    ls[t] = s;
    __syncthreads();
    for (int d = 1; d < 1024; d <<= 1) {
        int u = (t >= d) ? ls[t - d] : 0;
        __syncthreads();
        ls[t] += u;
        __syncthreads();
    }
    int run = ls[t] - s;
    for (int k = 0; k < per; ++k) {
        int i = base + k;
        if (i < Nn) {
            offs[i] = run;
            run += cnt[i];
        }
    }
}

__global__ __launch_bounds__(256) void scatter_kernel(const int* __restrict__ row,
                                                      const int* __restrict__ col,
                                                      const int* __restrict__ offs,
                                                      int* __restrict__ tmpc,
                                                      int* __restrict__ sortedIds,
                                                      int* __restrict__ rowS,
                                                      int* __restrict__ colS, int E)
{
    int e = blockIdx.x * 256 + threadIdx.x;
    if (e < E) {
        int c = col[e];
        int p = offs[c] + atomicAdd(&tmpc[c], 1);
        sortedIds[p] = e;
        rowS[p] = row[e];
        colS[p] = c;
    }
}

// ---------------------------------------------------------------------------
// Encoder: out(bf16) = relu(X[M,16] @ W[16,128] + b)
__global__ __launch_bounds__(256) void enc_kernel(const float* __restrict__ X,
                                                  const float* __restrict__ W,
                                                  const float* __restrict__ bias,
                                                  unsigned short* __restrict__ out, int M)
{
    __shared__ float sW[F_IN * H];
    __shared__ float sb[H];
    int t = threadIdx.x;
    reinterpret_cast<float4*>(sW)[t]       = reinterpret_cast<const float4*>(W)[t];
    reinterpret_cast<float4*>(sW)[t + 256] = reinterpret_cast<const float4*>(W)[t + 256];
    if (t < H) sb[t] = bias[t];
    __syncthreads();
    int row = blockIdx.x * 2 + (t >> 7);
    if (row >= M) return;
    int j = t & 127;
    float acc = sb[j];
#pragma unroll
    for (int k = 0; k < F_IN; ++k)
        acc += X[(size_t)row * F_IN + k] * sW[k * H + j];
    out[(size_t)row * H + j] = f2bf(fmaxf(acc, 0.f));
}

// Gather-encoder: out[p](bf16) = relu(X[sortedIds[p],16] @ W + b)
__global__ __launch_bounds__(256) void enc_gather_kernel(const float* __restrict__ X,
                                                         const int* __restrict__ sortedIds,
                                                         const float* __restrict__ W,
                                                         const float* __restrict__ bias,
                                                         unsigned short* __restrict__ out,
                                                         int M)
{
    __shared__ float sW[F_IN * H];
    __shared__ float sb[H];
    int t = threadIdx.x;
    reinterpret_cast<float4*>(sW)[t]       = reinterpret_cast<const float4*>(W)[t];
    reinterpret_cast<float4*>(sW)[t + 256] = reinterpret_cast<const float4*>(W)[t + 256];
    if (t < H) sb[t] = bias[t];
    __syncthreads();
    int p = blockIdx.x * 2 + (t >> 7);
    if (p >= M) return;
    int src = sortedIds[p];
    int j = t & 127;
    float acc = sb[j];
#pragma unroll
    for (int k = 0; k < F_IN; ++k)
        acc += X[(size_t)src * F_IN + k] * sW[k * H + j];
    out[(size_t)p * H + j] = f2bf(fmaxf(acc, 0.f));
}

// ---------------------------------------------------------------------------
// Fused edge kernel, 512 threads (8 waves x 16-col strips):
//   e'[p] = relu(bn_e(e[p])@W3 + bn_h(h[rowS])@W1 + bn_h(h[colS])@W2 + be)
//   m     = relu(e'@U2 + bn_h(h[rowS])@U1 + b1)
//   aggsum[col] += segment-MEAN partials (mbuf, 4-way) ; fused e'-stats
//   e' written to global via coalesced LDS stage-out.
__global__ __launch_bounds__(512, 3) void edge_kernel(unsigned short* eb,
                                                      const int* __restrict__ rowS,
                                                      const int* __restrict__ colS,
                                                      const int* __restrict__ cnt,
                                                      const unsigned short* __restrict__ hb,
                                                      const short8* __restrict__ wfrL,
                                                      const float* __restrict__ be,
                                                      const float* __restrict__ b1,
                                                      float* __restrict__ aggsum, int E,
                                                      const float* __restrict__ Sh,
                                                      const float* __restrict__ gh,
                                                      const float* __restrict__ bh,
                                                      float invN,
                                                      const float* __restrict__ Se,
                                                      const float* __restrict__ ge,
                                                      const float* __restrict__ beB,
                                                      float invE,
                                                      float* __restrict__ eStats)
{
    __shared__ __align__(16) unsigned char smem[64 * 128 * 6 + 256 + 256 + 2048];
    unsigned short* sE  = (unsigned short*)smem;          // 16 KB  e (bf16)
    unsigned short* sHt = sE + 64 * 128;                  // 16 KB  h[rowS] (bf16)
    unsigned short* sHc = sHt + 64 * 128;                 // 16 KB  h[colS] (bf16)
    float*          mbuf = (float*)smem;                  // 32 KB overlay sE+sHt
    int*            scol = (int*)(smem + 64 * 128 * 6);          // 256 B
    float*          sinv = (float*)(smem + 64 * 128 * 6 + 256);  // 256 B
    float*          bnp  = (float*)(smem + 64 * 128 * 6 + 512);  // 2 KB

    const int t = threadIdx.x, lane = t & 63, w = t >> 6;
    const int e0 = blockIdx.x * 64;
    const int g = lane >> 4, c0 = lane & 15;
    const int j = 16 * w + c0;        // this lane's output column

    if (t < 64) {
        int cc = colS[(e0 + t < E) ? (e0 + t) : (E - 1)];
        scol[t] = cc;
        int c = cnt[cc];
        sinv[t] = 1.f / (float)(c > 1 ? c : 1);
    }
    if (t >= 64 && t < 192)      bn_param(Sh, gh, bh, invN, t - 64, bnp, bnp + 128);
    else if (t >= 192 && t < 320) bn_param(Se, ge, beB, invE, t - 192, bnp + 256, bnp + 384);
    __syncthreads();   // bnp + scol ready

    stage_aff(eb, sE, e0, E, t, bnp + 256, bnp + 384);
    stage_aff_gather(hb, rowS, sHt, e0, E, t, bnp, bnp + 128);
    {
        int Mt = E - e0; if (Mt > 64) Mt = 64;
        stage_aff_gather(hb, scol, sHc, 0, Mt, t, bnp, bnp + 128);
    }

    short8 wf[4];
    f32x4 acc[4];
    zero_acc_h(acc);
    load_wfrag_h(wfrL + 2 * 2048, w, lane, wf);   // W3
    __syncthreads();
    mfma_gemm_h(sE, wf, acc, lane);
    load_wfrag_h(wfrL + 0 * 2048, w, lane, wf);   // W1
    mfma_gemm_h(sHt, wf, acc, lane);
    load_wfrag_h(wfrL + 1 * 2048, w, lane, wf);   // W2 (B-term)
    mfma_gemm_h(sHc, wf, acc, lane);
    __syncthreads();   // all reads of sE done -> safe to overwrite with e'

    // epilogue 1: e' = relu(acc + be) -> sE (swizzled) + stats in registers
    float s1 = 0.f, s2 = 0.f;
    {
        float bej = be[j];
#pragma unroll
        for (int fr = 0; fr < 4; ++fr)
#pragma unroll
            for (int r = 0; r < 4; ++r) {
                int Rl = 16 * fr + 4 * g + r;
                int p  = e0 + Rl;
                float v = acc[fr][r] + bej;
                v = fmaxf(v, 0.f);
                unsigned short vb = f2bf(v);
                if (p < E) {
                    s1 += v;
                    s2 += v * v;
                }
                sE[(Rl << 7) + (j ^ ((Rl & 7) << 3))] = vb;
            }
    }
    __syncthreads();   // sE complete

    // coalesced e' stage-out: 2 x 16B stores per thread (reads sE, unswizzled)
#pragma unroll
    for (int i = 0; i < 2; ++i) {
        int cid = t + 512 * i;
        int row = cid >> 4;
        int ck  = cid & 15;
        int p   = e0 + row;
        if (p < E) {
            short8 v = *(const short8*)(sE + (row << 7) + ((ck ^ (row & 7)) << 3));
            *(short8*)(eb + (size_t)p * H + ck * 8) = v;
        }
    }

    // GEMM2: m = e'@U2 + bn_h(h[rowS])@U1
    zero_acc_h(acc);
    load_wfrag_h(wfrL + 4 * 2048, w, lane, wf);   // U2
    mfma_gemm_h(sE, wf, acc, lane);
    load_wfrag_h(wfrL + 3 * 2048, w, lane, wf);   // U1
    mfma_gemm_h(sHt, wf, acc, lane);
    __syncthreads();   // all GEMM2 LDS reads done -> mbuf overlay safe

    // epilogue 2: m -> mbuf (swizzled)
    {
        float b1j = b1[j];
#pragma unroll
        for (int fr = 0; fr < 4; ++fr)
#pragma unroll
            for (int r = 0; r < 4; ++r) {
                int Rl = 16 * fr + 4 * g + r;
                float v = fmaxf(acc[fr][r] + b1j, 0.f);
                mbuf[(Rl << 7) + (j ^ (((Rl >> 2) & 3) << 3))] = v;
            }
    }
    __syncthreads();

    // segmented reduction, 4-way parallel over row quarters (512 threads)
    {
        int jc = t & 127, q = t >> 7;
        int rbeg = q * 16, rend = rbeg + 16;
        int rlim = E - e0;
        float run = 0.f;
        int cur = scol[rbeg];
        for (int row = rbeg; row < rend; ++row) {
            int cc = scol[row];
            float v = mbuf[(row << 7) + (jc ^ (((row >> 2) & 3) << 3))];
            if (cc != cur) {
                if (run != 0.f)
                    atomicAdd(&aggsum[(size_t)cur * H + jc], run * sinv[row - 1]);
                run = 0.f;
                cur = cc;
            }
            if (row < rlim) run += v;
        }
        if (run != 0.f)
            atomicAdd(&aggsum[(size_t)cur * H + jc], run * sinv[rend - 1]);
    }

    // fused e'-stats
    {
        float a = s1, b = s2;
        a += __shfl_xor(a, 16); a += __shfl_xor(a, 32);
        b += __shfl_xor(b, 16); b += __shfl_xor(b, 32);
        if (g == 0) {
            atomicAdd(&eStats[j], a);
            atomicAdd(&eStats[H + j], b);
        }
    }
}

// ---------------------------------------------------------------------------
// Node update, 512 threads: h = relu(bn_h(h)@V1 + aggmean@V2 + b2);
// fused h-stats; zeroes its aggsum rows.
__global__ __launch_bounds__(512, 4) void node_kernel(unsigned short* hb,
                                                      float* __restrict__ aggsum,
                                                      const short8* __restrict__ wfrL,
                                                      const float* __restrict__ b2, int M,
                                                      const float* __restrict__ Sh,
                                                      const float* __restrict__ gh,
                                                      const float* __restrict__ bh,
                                                      float invN,
                                                      float* __restrict__ hStats)
{
    __shared__ __align__(16) unsigned short sA[64 * 128];
    __shared__ __align__(16) unsigned short sB[64 * 128];
    __shared__ float bnp[256];
    const int t = threadIdx.x, lane = t & 63, w = t >> 6;
    const int r0 = blockIdx.x * 64;
    const int g = lane >> 4, c0 = lane & 15;
    const int j = 16 * w + c0;
    if (t < 128) bn_param(Sh, gh, bh, invN, t, bnp, bnp + 128);
    __syncthreads();
    stage_aff(hb, sA, r0, M, t, bnp, bnp + 128);
    stage_agg_bf16(aggsum, sB, r0, M, t);   // also zeroes consumed rows
    short8 wf[4];
    f32x4 acc[4];
    zero_acc_h(acc);
    load_wfrag_h(wfrL + 5 * 2048, w, lane, wf);   // V1
    __syncthreads();
    mfma_gemm_h(sA, wf, acc, lane);
    load_wfrag_h(wfrL + 6 * 2048, w, lane, wf);   // V2
    mfma_gemm_h(sB, wf, acc, lane);
    float s1 = 0.f, s2 = 0.f;
    {
        float bj = b2[j];
#pragma unroll
        for (int fr = 0; fr < 4; ++fr)
#pragma unroll
            for (int r = 0; r < 4; ++r) {
                int row = r0 + 16 * fr + 4 * g + r;
                if (row < M) {
                    float v = fmaxf(acc[fr][r] + bj, 0.f);
                    hb[(size_t)row * H + j] = f2bf(v);
                    s1 += v;
                    s2 += v * v;
                }
            }
    }
    {
        float a = s1, b = s2;
        a += __shfl_xor(a, 16); a += __shfl_xor(a, 32);
        b += __shfl_xor(b, 16); b += __shfl_xor(b, 32);
        if (g == 0) {
            atomicAdd(&hStats[j], a);
            atomicAdd(&hStats[H + j], b);
        }
    }
}

// ---------------------------------------------------------------------------
// Final readout: out = [mean(h) | mean(e)] @ reg_w + reg_b
__global__ __launch_bounds__(256) void final_kernel(const float* __restrict__ hsum,
                                                    const float* __restrict__ esum,
                                                    const float* __restrict__ reg_w,
                                                    const float* __restrict__ reg_b,
                                                    float* __restrict__ out,
                                                    float invN, float invE)
{
    __shared__ float red[256];
    int t = threadIdx.x;
    float v = (t < 128) ? hsum[t] * invN * reg_w[t]
                        : esum[t - 128] * invE * reg_w[t];
    red[t] = v;
    __syncthreads();
    for (int s = 128; s > 0; s >>= 1) {
        if (t < s) red[t] += red[t + s];
        __syncthreads();
    }
    if (t == 0) out[0] = red[0] + reg_b[0];
}

// ---------------------------------------------------------------------------
extern "C" void kernel_launch(void* const* d_in, const int* in_sizes, int n_in,
                              void* d_out, int out_size, void* d_ws, size_t ws_size,
                              hipStream_t stream)
{
    const float* x          = (const float*)d_in[0];
    const int*   edge_index = (const int*)  d_in[1];
    const float* edge_attr  = (const float*)d_in[2];
    const float* enc_node_w = (const float*)d_in[3];
    const float* enc_node_b = (const float*)d_in[4];
    const float* enc_edge_w = (const float*)d_in[5];
    const float* enc_edge_b = (const float*)d_in[6];
    const float* edge_w     = (const float*)d_in[7];
    const float* edge_b     = (const float*)d_in[8];
    const float* n1_w       = (const float*)d_in[9];
    const float* n1_b       = (const float*)d_in[10];
    const float* n2_w       = (const float*)d_in[11];
    const float* n2_b       = (const float*)d_in[12];
    const float* bn_node_g  = (const float*)d_in[13];
    const float* bn_node_b  = (const float*)d_in[14];
    const float* bn_edge_g  = (const float*)d_in[15];
    const float* bn_edge_b  = (const float*)d_in[16];
    const float* reg_w      = (const float*)d_in[17];
    const float* reg_b      = (const float*)d_in[18];

    const int N = in_sizes[0] / F_IN;
    const int E = in_sizes[1] / 2;
    const size_t NH = (size_t)N * H;
    const size_t EH = (size_t)E * H;

    float* ws     = (float*)d_ws;
    float* aggsum = ws;                 // [N,128] f32 (zeroed once; node re-zeroes)
    float* statsA = aggsum + NH;        // 512
    float* statsB = statsA + 512;       // 512
    short8* wfr   = (short8*)(statsB + 512);        // 21*2048 short8 = 672 KB
    unsigned short* hbuf = (unsigned short*)(wfr + 21 * 2048);  // [N,128] bf16
    unsigned short* ebuf = hbuf + NH;                           // [E,128] bf16 (col-sorted)
    int*   cnt_i  = (int*)(ebuf + EH);      // [N]
    int*   tmpc   = cnt_i + N;              // [N]
    int*   offs   = tmpc + N;               // [N+1]
    int*   sortedIds = offs + N + 1;        // [E]
    int*   rowS   = sortedIds + E;          // [E]
    int*   colS   = rowS + E;               // [E]

    const int* row_idx = edge_index;
    const int* col_idx = edge_index + E;
    const float invN = 1.f / (float)N;
    const float invE = 1.f / (float)E;

    // one-time: sort edges by col; bf16 weight fragments; encoders
    (void)hipMemsetAsync(cnt_i, 0, (size_t)2 * N * sizeof(int), stream);
    (void)hipMemsetAsync(aggsum, 0, NH * sizeof(float), stream);
    hist_kernel<<<(E + 255) / 256, 256, 0, stream>>>(col_idx, cnt_i, E);
    scan_kernel<<<1, 1024, 0, stream>>>(cnt_i, offs, N);
    scatter_kernel<<<(E + 255) / 256, 256, 0, stream>>>(row_idx, col_idx, offs, tmpc,
                                                        sortedIds, rowS, colS, E);
    wbf16_kernel<<<21, 256, 0, stream>>>(edge_w, n1_w, n2_w, wfr);

    enc_kernel<<<(N + 1) / 2, 256, 0, stream>>>(x, enc_node_w, enc_node_b, hbuf, N);
    enc_gather_kernel<<<(E + 1) / 2, 256, 0, stream>>>(edge_attr, sortedIds,
                                                       enc_edge_w, enc_edge_b, ebuf, E);

    const int nodeBlocks = (N + 63) / 64;
    const int edgeBlocks = (E + 63) / 64;

    for (int i = 0; i < 3; ++i) {
        float*       Scur  = (i & 1) ? statsB : statsA;
        const float* Sprev = (i == 0) ? nullptr : ((i & 1) ? statsA : statsB);
        const float* Sh = Sprev;
        const float* Se = Sprev ? Sprev + 256 : nullptr;
        const short8* wfrL = wfr + (size_t)i * 7 * 2048;
        (void)hipMemsetAsync(Scur, 0, 512 * sizeof(float), stream);
        edge_kernel<<<edgeBlocks, 512, 0, stream>>>(
            ebuf, rowS, colS, cnt_i, hbuf, wfrL,
            edge_b + i * H, n1_b + i * H,
            aggsum, E,
            Sh, bn_node_g, bn_node_b, invN,
            Se, bn_edge_g, bn_edge_b, invE,
            Scur + 256);
        node_kernel<<<nodeBlocks, 512, 0, stream>>>(
            hbuf, aggsum, wfrL, n2_b + i * H, N,
            Sh, bn_node_g, bn_node_b, invN,
            Scur);
    }
    // i=2 wrote statsA
    final_kernel<<<1, 256, 0, stream>>>(statsA, statsA + 256, reg_w, reg_b,
                                        (float*)d_out, invN, invE);
}

// Round 24
// 646.107 us; speedup vs baseline: 1.2294x; 1.1423x over previous
//
#include <hip/hip_runtime.h>

#define H 128
#define F_IN 16
#define BNEPS 1e-5f

typedef __attribute__((ext_vector_type(8))) short short8;
typedef __attribute__((ext_vector_type(4))) float f32x4;

// f32 -> bf16 round-to-nearest-even
__device__ __forceinline__ unsigned short f2bf(float f)
{
    unsigned u = __builtin_bit_cast(unsigned, f);
    u += 0x7FFFu + ((u >> 16) & 1u);
    return (unsigned short)(u >> 16);
}
__device__ __forceinline__ float bf2f(unsigned short h)
{
    return __builtin_bit_cast(float, (unsigned)h << 16);
}

// BN affine params for feature j: s[j], t[j] (identity if S==nullptr)
__device__ __forceinline__ void bn_param(const float* __restrict__ S,
                                         const float* __restrict__ g,
                                         const float* __restrict__ b,
                                         float invM, int j,
                                         float* __restrict__ sS, float* __restrict__ sT)
{
    float s = 1.f, tt = 0.f;
    if (S) {
        float mean = S[j] * invM;
        float var  = S[H + j] * invM - mean * mean;
        s  = rsqrtf(var + BNEPS) * g[j];
        tt = b[j] - mean * s;
    }
    sS[j] = s;
    sT[j] = tt;
}

// ---------------------------------------------------------------------------
// 512-thread staging: 64x128 bf16 tile with per-feature affine into swizzled
// LDS. element (row,k) -> ushort idx row*128 + (k ^ ((row&7)<<3))
__device__ __forceinline__ void stage_aff(const unsigned short* __restrict__ src,
                                          unsigned short* sA, int r0, int M, int t,
                                          const float* __restrict__ sS,
                                          const float* __restrict__ sT)
{
#pragma unroll
    for (int i = 0; i < 2; ++i) {
        int cid  = t + 512 * i;
        int row  = cid >> 4;
        int ck   = cid & 15;
        int grow = r0 + row;
        short8 v = (short8)0;
        if (grow < M) {
            v = *(const short8*)(src + (size_t)grow * H + ck * 8);
            int j0 = ck * 8;
#pragma unroll
            for (int j = 0; j < 8; ++j)
                v[j] = (short)f2bf(bf2f((unsigned short)v[j]) * sS[j0 + j] + sT[j0 + j]);
        }
        *(short8*)(sA + (row << 7) + ((ck ^ (row & 7)) << 3)) = v;
    }
}

// Gather variant: tile row i holds src[idx[p0+i]], same affine.
__device__ __forceinline__ void stage_aff_gather(const unsigned short* __restrict__ src,
                                                 const int* __restrict__ idx,
                                                 unsigned short* sA, int p0, int M, int t,
                                                 const float* __restrict__ sS,
                                                 const float* __restrict__ sT)
{
#pragma unroll
    for (int i = 0; i < 2; ++i) {
        int cid = t + 512 * i;
        int row = cid >> 4;
        int ck  = cid & 15;
        int p   = p0 + row;
        short8 v = (short8)0;
        if (p < M) {
            v = *(const short8*)(src + (size_t)idx[p] * H + ck * 8);
            int j0 = ck * 8;
#pragma unroll
            for (int j = 0; j < 8; ++j)
                v[j] = (short)f2bf(bf2f((unsigned short)v[j]) * sS[j0 + j] + sT[j0 + j]);
        }
        *(short8*)(sA + (row << 7) + ((ck ^ (row & 7)) << 3)) = v;
    }
}

// aggsum holds per-node MEANS -> convert to bf16; then zero rows for next layer
__device__ __forceinline__ void stage_agg_bf16(float* __restrict__ aggsum,
                                               unsigned short* sA, int r0, int M, int t)
{
#pragma unroll
    for (int i = 0; i < 2; ++i) {
        int cid  = t + 512 * i;
        int row  = cid >> 4;
        int ck   = cid & 15;
        int grow = r0 + row;
        short8 ph = (short8)0;
        if (grow < M) {
            float4* q = (float4*)(aggsum + (size_t)grow * H + ck * 8);
            float4 a = q[0], b = q[1];
            float xs[8] = {a.x, a.y, a.z, a.w, b.x, b.y, b.z, b.w};
#pragma unroll
            for (int j = 0; j < 8; ++j) ph[j] = (short)f2bf(xs[j]);
            q[0] = make_float4(0.f, 0.f, 0.f, 0.f);
            q[1] = make_float4(0.f, 0.f, 0.f, 0.f);
        }
        *(short8*)(sA + (row << 7) + ((ck ^ (row & 7)) << 3)) = ph;
    }
}

// ---------------------------------------------------------------------------
// One-time weight bf16 fragment precompute (21 matrices, unscaled).
__global__ __launch_bounds__(256) void wbf16_kernel(const float* __restrict__ edge_w,
                                                    const float* __restrict__ n1_w,
                                                    const float* __restrict__ n2_w,
                                                    short8* __restrict__ out)
{
    int m = blockIdx.x;
    int layer = m / 7, k = m % 7;
    const float* W = (k < 3) ? edge_w + (size_t)layer * 384 * H + (size_t)k * H * H
                   : (k < 5) ? n1_w + (size_t)layer * 256 * H + (size_t)(k - 3) * H * H
                             : n2_w + (size_t)layer * 256 * H + (size_t)(k - 5) * H * H;
    short8* oh = out + (size_t)m * 2048;
    for (int e = threadIdx.x; e < 2048; e += 256) {
        int jbB = e >> 9, s = (e >> 7) & 3, c = (e >> 6) & 1, lane = e & 63;
        int g = lane >> 4, c0 = lane & 15;
        short8 hi;
#pragma unroll
        for (int j = 0; j < 8; ++j)
            hi[j] = (short)f2bf(W[(size_t)(32 * s + 8 * g + j) * H + jbB * 32 + 16 * c + c0]);
        oh[e] = hi;
    }
}

// Wave w (0..7) owns cols [16w,16w+16): fragment idx jbB=w>>1, cB=w&1.
__device__ __forceinline__ void load_wfrag_h(const short8* __restrict__ Wp, int w,
                                             int lane, short8 wf[4])
{
    int base = ((w >> 1) * 8 + (w & 1)) * 64 + lane;
#pragma unroll
    for (int s = 0; s < 4; ++s)
        wf[s] = Wp[base + s * 128];
}

// acc[fr] += sA(64x128 bf16, swizzled) @ Wf(128x16 bf16)   (16 MFMA)
__device__ __forceinline__ void mfma_gemm_h(const unsigned short* sA, const short8 wf[4],
                                            f32x4 acc[4], int lane)
{
    const int g = lane >> 4, r = lane & 15;
#pragma unroll
    for (int s = 0; s < 4; ++s) {
        short8 a4[4];
#pragma unroll
        for (int fr = 0; fr < 4; ++fr) {
            int row = 16 * fr + r;
            int ck  = (4 * s + g) ^ (row & 7);
            a4[fr] = *(const short8*)(sA + (row << 7) + (ck << 3));
        }
#pragma unroll
        for (int fr = 0; fr < 4; ++fr)
            acc[fr] = __builtin_amdgcn_mfma_f32_16x16x32_bf16(a4[fr], wf[s], acc[fr], 0, 0, 0);
    }
}

__device__ __forceinline__ void zero_acc_h(f32x4 acc[4])
{
#pragma unroll
    for (int fr = 0; fr < 4; ++fr) {
        acc[fr][0] = 0.f; acc[fr][1] = 0.f; acc[fr][2] = 0.f; acc[fr][3] = 0.f;
    }
}

// ---------------------------------------------------------------------------
// One-time sort machinery (edge_index is layer-invariant)
__global__ __launch_bounds__(256) void hist_kernel(const int* __restrict__ col,
                                                   int* __restrict__ cnt, int E)
{
    int e = blockIdx.x * 256 + threadIdx.x;
    if (e < E) atomicAdd(&cnt[col[e]], 1);
}

// Parallel 3-phase exclusive scan over cnt[0..Nn) -> offs.
// scanA: per-1024 chunk: offs = within-chunk exclusive prefix; bsum[b] = chunk sum
__global__ __launch_bounds__(256) void scanA_kernel(const int* __restrict__ cnt,
                                                    int* __restrict__ offs,
                                                    int* __restrict__ bsum, int Nn)
{
    __shared__ int ls[256];
    int b = blockIdx.x, t = threadIdx.x;
    int base = b * 1024 + t * 4;
    int v0 = (base + 0 < Nn) ? cnt[base + 0] : 0;
    int v1 = (base + 1 < Nn) ? cnt[base + 1] : 0;
    int v2 = (base + 2 < Nn) ? cnt[base + 2] : 0;
    int v3 = (base + 3 < Nn) ? cnt[base + 3] : 0;
    int s = v0 + v1 + v2 + v3;
    ls[t] = s;
    __syncthreads();
    for (int d = 1; d < 256; d <<= 1) {
        int u = (t >= d) ? ls[t - d] : 0;
        __syncthreads();
        ls[t] += u;
        __syncthreads();
    }
    int run = ls[t] - s;   // exclusive prefix of this thread's 4 elements
    if (t == 255) bsum[b] = ls[255];
    if (base + 0 < Nn) { offs[base + 0] = run; run += v0; }
    if (base + 1 < Nn) { offs[base + 1] = run; run += v1; }
    if (base + 2 < Nn) { offs[base + 2] = run; run += v2; }
    if (base + 3 < Nn) { offs[base + 3] = run; run += v3; }
}

// scanB: single block, exclusive scan over nb (<=1024) block sums, in place
__global__ __launch_bounds__(1024) void scanB_kernel(int* __restrict__ bsum, int nb)
{
    __shared__ int ls[1024];
    int t = threadIdx.x;
    int s = (t < nb) ? bsum[t] : 0;
    ls[t] = s;
    __syncthreads();
    for (int d = 1; d < 1024; d <<= 1) {
        int u = (t >= d) ? ls[t - d] : 0;
        __syncthreads();
        ls[t] += u;
        __syncthreads();
    }
    if (t < nb) bsum[t] = ls[t] - s;   // exclusive
}

// scanC: offs[i] += bsum[chunk]
__global__ __launch_bounds__(256) void scanC_kernel(int* __restrict__ offs,
                                                    const int* __restrict__ bsum, int Nn)
{
    int b = blockIdx.x;
    int add = bsum[b];
    int base = b * 1024 + threadIdx.x * 4;
#pragma unroll
    for (int k = 0; k < 4; ++k)
        if (base + k < Nn) offs[base + k] += add;
}

__global__ __launch_bounds__(256) void scatter_kernel(const int* __restrict__ row,
                                                      const int* __restrict__ col,
                                                      const int* __restrict__ offs,
                                                      int* __restrict__ tmpc,
                                                      int* __restrict__ sortedIds,
                                                      int* __restrict__ rowS,
                                                      int* __restrict__ colS, int E)
{
    int e = blockIdx.x * 256 + threadIdx.x;
    if (e < E) {
        int c = col[e];
        int p = offs[c] + atomicAdd(&tmpc[c], 1);
        sortedIds[p] = e;
        rowS[p] = row[e];
        colS[p] = c;
    }
}

// ---------------------------------------------------------------------------
// Encoder: out(bf16) = relu(X[M,16] @ W[16,128] + b)
__global__ __launch_bounds__(256) void enc_kernel(const float* __restrict__ X,
                                                  const float* __restrict__ W,
                                                  const float* __restrict__ bias,
                                                  unsigned short* __restrict__ out, int M)
{
    __shared__ float sW[F_IN * H];
    __shared__ float sb[H];
    int t = threadIdx.x;
    reinterpret_cast<float4*>(sW)[t]       = reinterpret_cast<const float4*>(W)[t];
    reinterpret_cast<float4*>(sW)[t + 256] = reinterpret_cast<const float4*>(W)[t + 256];
    if (t < H) sb[t] = bias[t];
    __syncthreads();
    int row = blockIdx.x * 2 + (t >> 7);
    if (row >= M) return;
    int j = t & 127;
    float acc = sb[j];
#pragma unroll
    for (int k = 0; k < F_IN; ++k)
        acc += X[(size_t)row * F_IN + k] * sW[k * H + j];
    out[(size_t)row * H + j] = f2bf(fmaxf(acc, 0.f));
}

// Gather-encoder: out[p](bf16) = relu(X[sortedIds[p],16] @ W + b)
__global__ __launch_bounds__(256) void enc_gather_kernel(const float* __restrict__ X,
                                                         const int* __restrict__ sortedIds,
                                                         const float* __restrict__ W,
                                                         const float* __restrict__ bias,
                                                         unsigned short* __restrict__ out,
                                                         int M)
{
    __shared__ float sW[F_IN * H];
    __shared__ float sb[H];
    int t = threadIdx.x;
    reinterpret_cast<float4*>(sW)[t]       = reinterpret_cast<const float4*>(W)[t];
    reinterpret_cast<float4*>(sW)[t + 256] = reinterpret_cast<const float4*>(W)[t + 256];
    if (t < H) sb[t] = bias[t];
    __syncthreads();
    int p = blockIdx.x * 2 + (t >> 7);
    if (p >= M) return;
    int src = sortedIds[p];
    int j = t & 127;
    float acc = sb[j];
#pragma unroll
    for (int k = 0; k < F_IN; ++k)
        acc += X[(size_t)src * F_IN + k] * sW[k * H + j];
    out[(size_t)p * H + j] = f2bf(fmaxf(acc, 0.f));
}

// ---------------------------------------------------------------------------
// Fused edge kernel, 512 threads (8 waves x 16-col strips):
//   e'[p] = relu(bn_e(e[p])@W3 + bn_h(h[rowS])@W1 + bn_h(h[colS])@W2 + be)
//   m     = relu(e'@U2 + bn_h(h[rowS])@U1 + b1)
//   aggsum[col] += segment-MEAN partials (mbuf, 4-way) ; fused e'-stats
//   e' written to global via coalesced LDS stage-out.
__global__ __launch_bounds__(512, 3) void edge_kernel(unsigned short* eb,
                                                      const int* __restrict__ rowS,
                                                      const int* __restrict__ colS,
                                                      const int* __restrict__ cnt,
                                                      const unsigned short* __restrict__ hb,
                                                      const short8* __restrict__ wfrL,
                                                      const float* __restrict__ be,
                                                      const float* __restrict__ b1,
                                                      float* __restrict__ aggsum, int E,
                                                      const float* __restrict__ Sh,
                                                      const float* __restrict__ gh,
                                                      const float* __restrict__ bh,
                                                      float invN,
                                                      const float* __restrict__ Se,
                                                      const float* __restrict__ ge,
                                                      const float* __restrict__ beB,
                                                      float invE,
                                                      float* __restrict__ eStats)
{
    __shared__ __align__(16) unsigned char smem[64 * 128 * 6 + 256 + 256 + 2048];
    unsigned short* sE  = (unsigned short*)smem;          // 16 KB  e (bf16)
    unsigned short* sHt = sE + 64 * 128;                  // 16 KB  h[rowS] (bf16)
    unsigned short* sHc = sHt + 64 * 128;                 // 16 KB  h[colS] (bf16)
    float*          mbuf = (float*)smem;                  // 32 KB overlay sE+sHt
    int*            scol = (int*)(smem + 64 * 128 * 6);          // 256 B
    float*          sinv = (float*)(smem + 64 * 128 * 6 + 256);  // 256 B
    float*          bnp  = (float*)(smem + 64 * 128 * 6 + 512);  // 2 KB

    const int t = threadIdx.x, lane = t & 63, w = t >> 6;
    const int e0 = blockIdx.x * 64;
    const int g = lane >> 4, c0 = lane & 15;
    const int j = 16 * w + c0;        // this lane's output column

    if (t < 64) {
        int cc = colS[(e0 + t < E) ? (e0 + t) : (E - 1)];
        scol[t] = cc;
        int c = cnt[cc];
        sinv[t] = 1.f / (float)(c > 1 ? c : 1);
    }
    if (t >= 64 && t < 192)      bn_param(Sh, gh, bh, invN, t - 64, bnp, bnp + 128);
    else if (t >= 192 && t < 320) bn_param(Se, ge, beB, invE, t - 192, bnp + 256, bnp + 384);
    __syncthreads();   // bnp + scol ready

    stage_aff(eb, sE, e0, E, t, bnp + 256, bnp + 384);
    stage_aff_gather(hb, rowS, sHt, e0, E, t, bnp, bnp + 128);
    {
        int Mt = E - e0; if (Mt > 64) Mt = 64;
        stage_aff_gather(hb, scol, sHc, 0, Mt, t, bnp, bnp + 128);
    }

    short8 wf[4];
    f32x4 acc[4];
    zero_acc_h(acc);
    load_wfrag_h(wfrL + 2 * 2048, w, lane, wf);   // W3
    __syncthreads();
    mfma_gemm_h(sE, wf, acc, lane);
    load_wfrag_h(wfrL + 0 * 2048, w, lane, wf);   // W1
    mfma_gemm_h(sHt, wf, acc, lane);
    load_wfrag_h(wfrL + 1 * 2048, w, lane, wf);   // W2 (B-term)
    mfma_gemm_h(sHc, wf, acc, lane);
    __syncthreads();   // all reads of sE done -> safe to overwrite with e'

    // epilogue 1: e' = relu(acc + be) -> sE (swizzled) + stats in registers
    float s1 = 0.f, s2 = 0.f;
    {
        float bej = be[j];
#pragma unroll
        for (int fr = 0; fr < 4; ++fr)
#pragma unroll
            for (int r = 0; r < 4; ++r) {
                int Rl = 16 * fr + 4 * g + r;
                int p  = e0 + Rl;
                float v = acc[fr][r] + bej;
                v = fmaxf(v, 0.f);
                unsigned short vb = f2bf(v);
                if (p < E) {
                    s1 += v;
                    s2 += v * v;
                }
                sE[(Rl << 7) + (j ^ ((Rl & 7) << 3))] = vb;
            }
    }
    __syncthreads();   // sE complete

    // coalesced e' stage-out: 2 x 16B stores per thread (reads sE, unswizzled)
#pragma unroll
    for (int i = 0; i < 2; ++i) {
        int cid = t + 512 * i;
        int row = cid >> 4;
        int ck  = cid & 15;
        int p   = e0 + row;
        if (p < E) {
            short8 v = *(const short8*)(sE + (row << 7) + ((ck ^ (row & 7)) << 3));
            *(short8*)(eb + (size_t)p * H + ck * 8) = v;
        }
    }

    // GEMM2: m = e'@U2 + bn_h(h[rowS])@U1
    zero_acc_h(acc);
    load_wfrag_h(wfrL + 4 * 2048, w, lane, wf);   // U2
    mfma_gemm_h(sE, wf, acc, lane);
    load_wfrag_h(wfrL + 3 * 2048, w, lane, wf);   // U1
    mfma_gemm_h(sHt, wf, acc, lane);
    __syncthreads();   // all GEMM2 LDS reads done -> mbuf overlay safe

    // epilogue 2: m -> mbuf (swizzled)
    {
        float b1j = b1[j];
#pragma unroll
        for (int fr = 0; fr < 4; ++fr)
#pragma unroll
            for (int r = 0; r < 4; ++r) {
                int Rl = 16 * fr + 4 * g + r;
                float v = fmaxf(acc[fr][r] + b1j, 0.f);
                mbuf[(Rl << 7) + (j ^ (((Rl >> 2) & 3) << 3))] = v;
            }
    }
    __syncthreads();

    // segmented reduction, 4-way parallel over row quarters (512 threads)
    {
        int jc = t & 127, q = t >> 7;
        int rbeg = q * 16, rend = rbeg + 16;
        int rlim = E - e0;
        float run = 0.f;
        int cur = scol[rbeg];
        for (int row = rbeg; row < rend; ++row) {
            int cc = scol[row];
            float v = mbuf[(row << 7) + (jc ^ (((row >> 2) & 3) << 3))];
            if (cc != cur) {
                if (run != 0.f)
                    atomicAdd(&aggsum[(size_t)cur * H + jc], run * sinv[row - 1]);
                run = 0.f;
                cur = cc;
            }
            if (row < rlim) run += v;
        }
        if (run != 0.f)
            atomicAdd(&aggsum[(size_t)cur * H + jc], run * sinv[rend - 1]);
    }

    // fused e'-stats
    {
        float a = s1, b = s2;
        a += __shfl_xor(a, 16); a += __shfl_xor(a, 32);
        b += __shfl_xor(b, 16); b += __shfl_xor(b, 32);
        if (g == 0) {
            atomicAdd(&eStats[j], a);
            atomicAdd(&eStats[H + j], b);
        }
    }
}

// ---------------------------------------------------------------------------
// Node update, 512 threads: h = relu(bn_h(h)@V1 + aggmean@V2 + b2);
// fused h-stats; zeroes its aggsum rows.
__global__ __launch_bounds__(512, 4) void node_kernel(unsigned short* hb,
                                                      float* __restrict__ aggsum,
                                                      const short8* __restrict__ wfrL,
                                                      const float* __restrict__ b2, int M,
                                                      const float* __restrict__ Sh,
                                                      const float* __restrict__ gh,
                                                      const float* __restrict__ bh,
                                                      float invN,
                                                      float* __restrict__ hStats)
{
    __shared__ __align__(16) unsigned short sA[64 * 128];
    __shared__ __align__(16) unsigned short sB[64 * 128];
    __shared__ float bnp[256];
    const int t = threadIdx.x, lane = t & 63, w = t >> 6;
    const int r0 = blockIdx.x * 64;
    const int g = lane >> 4, c0 = lane & 15;
    const int j = 16 * w + c0;
    if (t < 128) bn_param(Sh, gh, bh, invN, t, bnp, bnp + 128);
    __syncthreads();
    stage_aff(hb, sA, r0, M, t, bnp, bnp + 128);
    stage_agg_bf16(aggsum, sB, r0, M, t);   // also zeroes consumed rows
    short8 wf[4];
    f32x4 acc[4];
    zero_acc_h(acc);
    load_wfrag_h(wfrL + 5 * 2048, w, lane, wf);   // V1
    __syncthreads();
    mfma_gemm_h(sA, wf, acc, lane);
    load_wfrag_h(wfrL + 6 * 2048, w, lane, wf);   // V2
    mfma_gemm_h(sB, wf, acc, lane);
    float s1 = 0.f, s2 = 0.f;
    {
        float bj = b2[j];
#pragma unroll
        for (int fr = 0; fr < 4; ++fr)
#pragma unroll
            for (int r = 0; r < 4; ++r) {
                int row = r0 + 16 * fr + 4 * g + r;
                if (row < M) {
                    float v = fmaxf(acc[fr][r] + bj, 0.f);
                    hb[(size_t)row * H + j] = f2bf(v);
                    s1 += v;
                    s2 += v * v;
                }
            }
    }
    {
        float a = s1, b = s2;
        a += __shfl_xor(a, 16); a += __shfl_xor(a, 32);
        b += __shfl_xor(b, 16); b += __shfl_xor(b, 32);
        if (g == 0) {
            atomicAdd(&hStats[j], a);
            atomicAdd(&hStats[H + j], b);
        }
    }
}

// ---------------------------------------------------------------------------
// Final readout: out = [mean(h) | mean(e)] @ reg_w + reg_b
__global__ __launch_bounds__(256) void final_kernel(const float* __restrict__ hsum,
                                                    const float* __restrict__ esum,
                                                    const float* __restrict__ reg_w,
                                                    const float* __restrict__ reg_b,
                                                    float* __restrict__ out,
                                                    float invN, float invE)
{
    __shared__ float red[256];
    int t = threadIdx.x;
    float v = (t < 128) ? hsum[t] * invN * reg_w[t]
                        : esum[t - 128] * invE * reg_w[t];
    red[t] = v;
    __syncthreads();
    for (int s = 128; s > 0; s >>= 1) {
        if (t < s) red[t] += red[t + s];
        __syncthreads();
    }
    if (t == 0) out[0] = red[0] + reg_b[0];
}

// ---------------------------------------------------------------------------
extern "C" void kernel_launch(void* const* d_in, const int* in_sizes, int n_in,
                              void* d_out, int out_size, void* d_ws, size_t ws_size,
                              hipStream_t stream)
{
    const float* x          = (const float*)d_in[0];
    const int*   edge_index = (const int*)  d_in[1];
    const float* edge_attr  = (const float*)d_in[2];
    const float* enc_node_w = (const float*)d_in[3];
    const float* enc_node_b = (const float*)d_in[4];
    const float* enc_edge_w = (const float*)d_in[5];
    const float* enc_edge_b = (const float*)d_in[6];
    const float* edge_w     = (const float*)d_in[7];
    const float* edge_b     = (const float*)d_in[8];
    const float* n1_w       = (const float*)d_in[9];
    const float* n1_b       = (const float*)d_in[10];
    const float* n2_w       = (const float*)d_in[11];
    const float* n2_b       = (const float*)d_in[12];
    const float* bn_node_g  = (const float*)d_in[13];
    const float* bn_node_b  = (const float*)d_in[14];
    const float* bn_edge_g  = (const float*)d_in[15];
    const float* bn_edge_b  = (const float*)d_in[16];
    const float* reg_w      = (const float*)d_in[17];
    const float* reg_b      = (const float*)d_in[18];

    const int N = in_sizes[0] / F_IN;
    const int E = in_sizes[1] / 2;
    const size_t NH = (size_t)N * H;
    const size_t EH = (size_t)E * H;

    // Workspace layout: one contiguous zero region up front.
    float* ws     = (float*)d_ws;
    float* aggsum = ws;                     // [N,128] f32
    float* stats  = aggsum + NH;            // 3 * 512 (S0,S1,S2, per-layer)
    int*   cnt_i  = (int*)(stats + 1536);   // [N]
    int*   tmpc   = cnt_i + N;              // [N]
    const size_t zeroFloats = NH + 1536 + 2 * (size_t)N;
    int*   offs   = tmpc + N;               // [N+1]
    int*   bsum   = offs + N + 1;           // [1024]
    int*   sortedIds = bsum + 1024;         // [E]
    int*   rowS   = sortedIds + E;          // [E]
    int*   colS   = rowS + E;               // [E]
    short8* wfr   = (short8*)((((uintptr_t)(colS + E)) + 15) & ~(uintptr_t)15);  // 21*2048
    unsigned short* hbuf = (unsigned short*)(wfr + 21 * 2048);  // [N,128] bf16
    unsigned short* ebuf = hbuf + NH;                           // [E,128] bf16 (col-sorted)

    const int* row_idx = edge_index;
    const int* col_idx = edge_index + E;
    const float invN = 1.f / (float)N;
    const float invE = 1.f / (float)E;
    const int nb = (N + 1023) / 1024;       // scan chunks (<=1024 for N<=1M)

    // one-time: single upfront memset; sort edges by col (parallel scan);
    // bf16 weight fragments; encoders
    (void)hipMemsetAsync(aggsum, 0, zeroFloats * sizeof(float), stream);
    hist_kernel<<<(E + 255) / 256, 256, 0, stream>>>(col_idx, cnt_i, E);
    scanA_kernel<<<nb, 256, 0, stream>>>(cnt_i, offs, bsum, N);
    scanB_kernel<<<1, 1024, 0, stream>>>(bsum, nb);
    scanC_kernel<<<nb, 256, 0, stream>>>(offs, bsum, N);
    scatter_kernel<<<(E + 255) / 256, 256, 0, stream>>>(row_idx, col_idx, offs, tmpc,
                                                        sortedIds, rowS, colS, E);
    wbf16_kernel<<<21, 256, 0, stream>>>(edge_w, n1_w, n2_w, wfr);

    enc_kernel<<<(N + 1) / 2, 256, 0, stream>>>(x, enc_node_w, enc_node_b, hbuf, N);
    enc_gather_kernel<<<(E + 1) / 2, 256, 0, stream>>>(edge_attr, sortedIds,
                                                       enc_edge_w, enc_edge_b, ebuf, E);

    const int nodeBlocks = (N + 63) / 64;
    const int edgeBlocks = (E + 63) / 64;

    for (int i = 0; i < 3; ++i) {
        float*       Scur  = stats + (size_t)i * 512;          // zeroed upfront
        const float* Sprev = (i == 0) ? nullptr : stats + (size_t)(i - 1) * 512;
        const float* Sh = Sprev;
        const float* Se = Sprev ? Sprev + 256 : nullptr;
        const short8* wfrL = wfr + (size_t)i * 7 * 2048;
        edge_kernel<<<edgeBlocks, 512, 0, stream>>>(
            ebuf, rowS, colS, cnt_i, hbuf, wfrL,
            edge_b + i * H, n1_b + i * H,
            aggsum, E,
            Sh, bn_node_g, bn_node_b, invN,
            Se, bn_edge_g, bn_edge_b, invE,
            Scur + 256);
        node_kernel<<<nodeBlocks, 512, 0, stream>>>(
            hbuf, aggsum, wfrL, n2_b + i * H, N,
            Sh, bn_node_g, bn_node_b, invN,
            Scur);
    }
    // layer 2 wrote stats+1024 (S2)
    final_kernel<<<1, 256, 0, stream>>>(stats + 1024, stats + 1024 + 256, reg_w, reg_b,
                                        (float*)d_out, invN, invE);
}

// Round 25
// 645.077 us; speedup vs baseline: 1.2313x; 1.0016x over previous
//
#include <hip/hip_runtime.h>

#define H 128
#define F_IN 16
#define BNEPS 1e-5f

typedef __attribute__((ext_vector_type(8))) short short8;
typedef __attribute__((ext_vector_type(4))) float f32x4;

// f32 -> bf16 round-to-nearest-even
__device__ __forceinline__ unsigned short f2bf(float f)
{
    unsigned u = __builtin_bit_cast(unsigned, f);
    u += 0x7FFFu + ((u >> 16) & 1u);
    return (unsigned short)(u >> 16);
}
__device__ __forceinline__ float bf2f(unsigned short h)
{
    return __builtin_bit_cast(float, (unsigned)h << 16);
}

// BN affine params for feature j: s[j], t[j] (identity if S==nullptr)
__device__ __forceinline__ void bn_param(const float* __restrict__ S,
                                         const float* __restrict__ g,
                                         const float* __restrict__ b,
                                         float invM, int j,
                                         float* __restrict__ sS, float* __restrict__ sT)
{
    float s = 1.f, tt = 0.f;
    if (S) {
        float mean = S[j] * invM;
        float var  = S[H + j] * invM - mean * mean;
        s  = rsqrtf(var + BNEPS) * g[j];
        tt = b[j] - mean * s;
    }
    sS[j] = s;
    sT[j] = tt;
}

// ---------------------------------------------------------------------------
// 512-thread staging: 64x128 bf16 tile with per-feature affine into swizzled
// LDS. element (row,k) -> ushort idx row*128 + (k ^ ((row&7)<<3))
__device__ __forceinline__ void stage_aff(const unsigned short* __restrict__ src,
                                          unsigned short* sA, int r0, int M, int t,
                                          const float* __restrict__ sS,
                                          const float* __restrict__ sT)
{
#pragma unroll
    for (int i = 0; i < 2; ++i) {
        int cid  = t + 512 * i;
        int row  = cid >> 4;
        int ck   = cid & 15;
        int grow = r0 + row;
        short8 v = (short8)0;
        if (grow < M) {
            v = *(const short8*)(src + (size_t)grow * H + ck * 8);
            int j0 = ck * 8;
#pragma unroll
            for (int j = 0; j < 8; ++j)
                v[j] = (short)f2bf(bf2f((unsigned short)v[j]) * sS[j0 + j] + sT[j0 + j]);
        }
        *(short8*)(sA + (row << 7) + ((ck ^ (row & 7)) << 3)) = v;
    }
}

// Gather variant: tile row i holds src[idx[p0+i]], same affine.
__device__ __forceinline__ void stage_aff_gather(const unsigned short* __restrict__ src,
                                                 const int* __restrict__ idx,
                                                 unsigned short* sA, int p0, int M, int t,
                                                 const float* __restrict__ sS,
                                                 const float* __restrict__ sT)
{
#pragma unroll
    for (int i = 0; i < 2; ++i) {
        int cid = t + 512 * i;
        int row = cid >> 4;
        int ck  = cid & 15;
        int p   = p0 + row;
        short8 v = (short8)0;
        if (p < M) {
            v = *(const short8*)(src + (size_t)idx[p] * H + ck * 8);
            int j0 = ck * 8;
#pragma unroll
            for (int j = 0; j < 8; ++j)
                v[j] = (short)f2bf(bf2f((unsigned short)v[j]) * sS[j0 + j] + sT[j0 + j]);
        }
        *(short8*)(sA + (row << 7) + ((ck ^ (row & 7)) << 3)) = v;
    }
}

// aggsum holds per-node MEANS -> convert to bf16; then zero rows for next layer
__device__ __forceinline__ void stage_agg_bf16(float* __restrict__ aggsum,
                                               unsigned short* sA, int r0, int M, int t)
{
#pragma unroll
    for (int i = 0; i < 2; ++i) {
        int cid  = t + 512 * i;
        int row  = cid >> 4;
        int ck   = cid & 15;
        int grow = r0 + row;
        short8 ph = (short8)0;
        if (grow < M) {
            float4* q = (float4*)(aggsum + (size_t)grow * H + ck * 8);
            float4 a = q[0], b = q[1];
            float xs[8] = {a.x, a.y, a.z, a.w, b.x, b.y, b.z, b.w};
#pragma unroll
            for (int j = 0; j < 8; ++j) ph[j] = (short)f2bf(xs[j]);
            q[0] = make_float4(0.f, 0.f, 0.f, 0.f);
            q[1] = make_float4(0.f, 0.f, 0.f, 0.f);
        }
        *(short8*)(sA + (row << 7) + ((ck ^ (row & 7)) << 3)) = ph;
    }
}

// ---------------------------------------------------------------------------
// One-time weight bf16 fragment precompute (21 matrices, unscaled).
__global__ __launch_bounds__(256) void wbf16_kernel(const float* __restrict__ edge_w,
                                                    const float* __restrict__ n1_w,
                                                    const float* __restrict__ n2_w,
                                                    short8* __restrict__ out)
{
    int m = blockIdx.x;
    int layer = m / 7, k = m % 7;
    const float* W = (k < 3) ? edge_w + (size_t)layer * 384 * H + (size_t)k * H * H
                   : (k < 5) ? n1_w + (size_t)layer * 256 * H + (size_t)(k - 3) * H * H
                             : n2_w + (size_t)layer * 256 * H + (size_t)(k - 5) * H * H;
    short8* oh = out + (size_t)m * 2048;
    for (int e = threadIdx.x; e < 2048; e += 256) {
        int jbB = e >> 9, s = (e >> 7) & 3, c = (e >> 6) & 1, lane = e & 63;
        int g = lane >> 4, c0 = lane & 15;
        short8 hi;
#pragma unroll
        for (int j = 0; j < 8; ++j)
            hi[j] = (short)f2bf(W[(size_t)(32 * s + 8 * g + j) * H + jbB * 32 + 16 * c + c0]);
        oh[e] = hi;
    }
}

// Wave w (0..7) owns cols [16w,16w+16): fragment idx jbB=w>>1, cB=w&1.
__device__ __forceinline__ void load_wfrag_h(const short8* __restrict__ Wp, int w,
                                             int lane, short8 wf[4])
{
    int base = ((w >> 1) * 8 + (w & 1)) * 64 + lane;
#pragma unroll
    for (int s = 0; s < 4; ++s)
        wf[s] = Wp[base + s * 128];
}

// acc[fr] += sA(64x128 bf16, swizzled) @ Wf(128x16 bf16)   (16 MFMA)
__device__ __forceinline__ void mfma_gemm_h(const unsigned short* sA, const short8 wf[4],
                                            f32x4 acc[4], int lane)
{
    const int g = lane >> 4, r = lane & 15;
#pragma unroll
    for (int s = 0; s < 4; ++s) {
        short8 a4[4];
#pragma unroll
        for (int fr = 0; fr < 4; ++fr) {
            int row = 16 * fr + r;
            int ck  = (4 * s + g) ^ (row & 7);
            a4[fr] = *(const short8*)(sA + (row << 7) + (ck << 3));
        }
#pragma unroll
        for (int fr = 0; fr < 4; ++fr)
            acc[fr] = __builtin_amdgcn_mfma_f32_16x16x32_bf16(a4[fr], wf[s], acc[fr], 0, 0, 0);
    }
}

__device__ __forceinline__ void zero_acc_h(f32x4 acc[4])
{
#pragma unroll
    for (int fr = 0; fr < 4; ++fr) {
        acc[fr][0] = 0.f; acc[fr][1] = 0.f; acc[fr][2] = 0.f; acc[fr][3] = 0.f;
    }
}

// ---------------------------------------------------------------------------
// One-time sort machinery (edge_index is layer-invariant)
__global__ __launch_bounds__(256) void hist_kernel(const int* __restrict__ col,
                                                   int* __restrict__ cnt, int E)
{
    int e = blockIdx.x * 256 + threadIdx.x;
    if (e < E) atomicAdd(&cnt[col[e]], 1);
}

// Parallel 3-phase exclusive scan over cnt[0..Nn) -> offs.
// scanA: per-1024 chunk: offs = within-chunk exclusive prefix; bsum[b] = chunk sum
__global__ __launch_bounds__(256) void scanA_kernel(const int* __restrict__ cnt,
                                                    int* __restrict__ offs,
                                                    int* __restrict__ bsum, int Nn)
{
    __shared__ int ls[256];
    int b = blockIdx.x, t = threadIdx.x;
    int base = b * 1024 + t * 4;
    int v0 = (base + 0 < Nn) ? cnt[base + 0] : 0;
    int v1 = (base + 1 < Nn) ? cnt[base + 1] : 0;
    int v2 = (base + 2 < Nn) ? cnt[base + 2] : 0;
    int v3 = (base + 3 < Nn) ? cnt[base + 3] : 0;
    int s = v0 + v1 + v2 + v3;
    ls[t] = s;
    __syncthreads();
    for (int d = 1; d < 256; d <<= 1) {
        int u = (t >= d) ? ls[t - d] : 0;
        __syncthreads();
        ls[t] += u;
        __syncthreads();
    }
    int run = ls[t] - s;   // exclusive prefix of this thread's 4 elements
    if (t == 255) bsum[b] = ls[255];
    if (base + 0 < Nn) { offs[base + 0] = run; run += v0; }
    if (base + 1 < Nn) { offs[base + 1] = run; run += v1; }
    if (base + 2 < Nn) { offs[base + 2] = run; run += v2; }
    if (base + 3 < Nn) { offs[base + 3] = run; run += v3; }
}

// scanB: single block, exclusive scan over nb (<=1024) block sums, in place
__global__ __launch_bounds__(1024) void scanB_kernel(int* __restrict__ bsum, int nb)
{
    __shared__ int ls[1024];
    int t = threadIdx.x;
    int s = (t < nb) ? bsum[t] : 0;
    ls[t] = s;
    __syncthreads();
    for (int d = 1; d < 1024; d <<= 1) {
        int u = (t >= d) ? ls[t - d] : 0;
        __syncthreads();
        ls[t] += u;
        __syncthreads();
    }
    if (t < nb) bsum[t] = ls[t] - s;   // exclusive
}

// scanC: offs[i] += bsum[chunk]
__global__ __launch_bounds__(256) void scanC_kernel(int* __restrict__ offs,
                                                    const int* __restrict__ bsum, int Nn)
{
    int b = blockIdx.x;
    int add = bsum[b];
    int base = b * 1024 + threadIdx.x * 4;
#pragma unroll
    for (int k = 0; k < 4; ++k)
        if (base + k < Nn) offs[base + k] += add;
}

__global__ __launch_bounds__(256) void scatter_kernel(const int* __restrict__ row,
                                                      const int* __restrict__ col,
                                                      const int* __restrict__ offs,
                                                      int* __restrict__ tmpc,
                                                      int* __restrict__ sortedIds,
                                                      int* __restrict__ rowS,
                                                      int* __restrict__ colS, int E)
{
    int e = blockIdx.x * 256 + threadIdx.x;
    if (e < E) {
        int c = col[e];
        int p = offs[c] + atomicAdd(&tmpc[c], 1);
        sortedIds[p] = e;
        rowS[p] = row[e];
        colS[p] = c;
    }
}

// ---------------------------------------------------------------------------
// Encoder: out(bf16) = relu(X[M,16] @ W[16,128] + b)
__global__ __launch_bounds__(256) void enc_kernel(const float* __restrict__ X,
                                                  const float* __restrict__ W,
                                                  const float* __restrict__ bias,
                                                  unsigned short* __restrict__ out, int M)
{
    __shared__ float sW[F_IN * H];
    __shared__ float sb[H];
    int t = threadIdx.x;
    reinterpret_cast<float4*>(sW)[t]       = reinterpret_cast<const float4*>(W)[t];
    reinterpret_cast<float4*>(sW)[t + 256] = reinterpret_cast<const float4*>(W)[t + 256];
    if (t < H) sb[t] = bias[t];
    __syncthreads();
    int row = blockIdx.x * 2 + (t >> 7);
    if (row >= M) return;
    int j = t & 127;
    float acc = sb[j];
#pragma unroll
    for (int k = 0; k < F_IN; ++k)
        acc += X[(size_t)row * F_IN + k] * sW[k * H + j];
    out[(size_t)row * H + j] = f2bf(fmaxf(acc, 0.f));
}

// Gather-encoder: out[p](bf16) = relu(X[sortedIds[p],16] @ W + b)
__global__ __launch_bounds__(256) void enc_gather_kernel(const float* __restrict__ X,
                                                         const int* __restrict__ sortedIds,
                                                         const float* __restrict__ W,
                                                         const float* __restrict__ bias,
                                                         unsigned short* __restrict__ out,
                                                         int M)
{
    __shared__ float sW[F_IN * H];
    __shared__ float sb[H];
    int t = threadIdx.x;
    reinterpret_cast<float4*>(sW)[t]       = reinterpret_cast<const float4*>(W)[t];
    reinterpret_cast<float4*>(sW)[t + 256] = reinterpret_cast<const float4*>(W)[t + 256];
    if (t < H) sb[t] = bias[t];
    __syncthreads();
    int p = blockIdx.x * 2 + (t >> 7);
    if (p >= M) return;
    int src = sortedIds[p];
    int j = t & 127;
    float acc = sb[j];
#pragma unroll
    for (int k = 0; k < F_IN; ++k)
        acc += X[(size_t)src * F_IN + k] * sW[k * H + j];
    out[(size_t)p * H + j] = f2bf(fmaxf(acc, 0.f));
}

// ---------------------------------------------------------------------------
// Fused edge kernel, 512 threads (8 waves x 16-col strips):
//   e'[p] = relu(bn_e(e[p])@W3 + bn_h(h[rowS])@W1 + bn_h(h[colS])@W2 + be)
//   m     = relu(e'@U2 + bn_h(h[rowS])@U1 + b1)
//   aggsum[col] += segment-MEAN partials (mbuf, 4-way) ; fused e'-stats
//   e' written to global via coalesced LDS stage-out.
__global__ __launch_bounds__(512, 3) void edge_kernel(unsigned short* eb,
                                                      const int* __restrict__ rowS,
                                                      const int* __restrict__ colS,
                                                      const int* __restrict__ cnt,
                                                      const unsigned short* __restrict__ hb,
                                                      const short8* __restrict__ wfrL,
                                                      const float* __restrict__ be,
                                                      const float* __restrict__ b1,
                                                      float* __restrict__ aggsum, int E,
                                                      const float* __restrict__ Sh,
                                                      const float* __restrict__ gh,
                                                      const float* __restrict__ bh,
                                                      float invN,
                                                      const float* __restrict__ Se,
                                                      const float* __restrict__ ge,
                                                      const float* __restrict__ beB,
                                                      float invE,
                                                      float* __restrict__ eStats)
{
    __shared__ __align__(16) unsigned char smem[64 * 128 * 6 + 256 + 256 + 2048];
    unsigned short* sE  = (unsigned short*)smem;          // 16 KB  e (bf16)
    unsigned short* sHt = sE + 64 * 128;                  // 16 KB  h[rowS] (bf16)
    unsigned short* sHc = sHt + 64 * 128;                 // 16 KB  h[colS] (bf16)
    float*          mbuf = (float*)smem;                  // 32 KB overlay sE+sHt
    int*            scol = (int*)(smem + 64 * 128 * 6);          // 256 B
    float*          sinv = (float*)(smem + 64 * 128 * 6 + 256);  // 256 B
    float*          bnp  = (float*)(smem + 64 * 128 * 6 + 512);  // 2 KB

    const int t = threadIdx.x, lane = t & 63, w = t >> 6;
    const int e0 = blockIdx.x * 64;
    const int g = lane >> 4, c0 = lane & 15;
    const int j = 16 * w + c0;        // this lane's output column

    if (t < 64) {
        int cc = colS[(e0 + t < E) ? (e0 + t) : (E - 1)];
        scol[t] = cc;
        int c = cnt[cc];
        sinv[t] = 1.f / (float)(c > 1 ? c : 1);
    }
    if (t >= 64 && t < 192)      bn_param(Sh, gh, bh, invN, t - 64, bnp, bnp + 128);
    else if (t >= 192 && t < 320) bn_param(Se, ge, beB, invE, t - 192, bnp + 256, bnp + 384);
    __syncthreads();   // bnp + scol ready

    stage_aff(eb, sE, e0, E, t, bnp + 256, bnp + 384);
    stage_aff_gather(hb, rowS, sHt, e0, E, t, bnp, bnp + 128);
    {
        int Mt = E - e0; if (Mt > 64) Mt = 64;
        stage_aff_gather(hb, scol, sHc, 0, Mt, t, bnp, bnp + 128);
    }

    short8 wf[4];
    f32x4 acc[4];
    zero_acc_h(acc);
    load_wfrag_h(wfrL + 2 * 2048, w, lane, wf);   // W3
    __syncthreads();
    mfma_gemm_h(sE, wf, acc, lane);
    load_wfrag_h(wfrL + 0 * 2048, w, lane, wf);   // W1
    mfma_gemm_h(sHt, wf, acc, lane);
    load_wfrag_h(wfrL + 1 * 2048, w, lane, wf);   // W2 (B-term)
    mfma_gemm_h(sHc, wf, acc, lane);
    __syncthreads();   // all reads of sE done -> safe to overwrite with e'

    // epilogue 1: e' = relu(acc + be) -> sE (swizzled) + stats in registers
    float s1 = 0.f, s2 = 0.f;
    {
        float bej = be[j];
#pragma unroll
        for (int fr = 0; fr < 4; ++fr)
#pragma unroll
            for (int r = 0; r < 4; ++r) {
                int Rl = 16 * fr + 4 * g + r;
                int p  = e0 + Rl;
                float v = acc[fr][r] + bej;
                v = fmaxf(v, 0.f);
                unsigned short vb = f2bf(v);
                if (p < E) {
                    s1 += v;
                    s2 += v * v;
                }
                sE[(Rl << 7) + (j ^ ((Rl & 7) << 3))] = vb;
            }
    }
    __syncthreads();   // sE complete

    // coalesced e' stage-out: 2 x 16B stores per thread (reads sE, unswizzled)
#pragma unroll
    for (int i = 0; i < 2; ++i) {
        int cid = t + 512 * i;
        int row = cid >> 4;
        int ck  = cid & 15;
        int p   = e0 + row;
        if (p < E) {
            short8 v = *(const short8*)(sE + (row << 7) + ((ck ^ (row & 7)) << 3));
            *(short8*)(eb + (size_t)p * H + ck * 8) = v;
        }
    }

    // GEMM2: m = e'@U2 + bn_h(h[rowS])@U1
    zero_acc_h(acc);
    load_wfrag_h(wfrL + 4 * 2048, w, lane, wf);   // U2
    mfma_gemm_h(sE, wf, acc, lane);
    load_wfrag_h(wfrL + 3 * 2048, w, lane, wf);   // U1
    mfma_gemm_h(sHt, wf, acc, lane);
    __syncthreads();   // all GEMM2 LDS reads done -> mbuf overlay safe

    // epilogue 2: m -> mbuf (swizzled)
    {
        float b1j = b1[j];
#pragma unroll
        for (int fr = 0; fr < 4; ++fr)
#pragma unroll
            for (int r = 0; r < 4; ++r) {
                int Rl = 16 * fr + 4 * g + r;
                float v = fmaxf(acc[fr][r] + b1j, 0.f);
                mbuf[(Rl << 7) + (j ^ (((Rl >> 2) & 3) << 3))] = v;
            }
    }
    __syncthreads();

    // segmented reduction, 4-way parallel over row quarters (512 threads)
    {
        int jc = t & 127, q = t >> 7;
        int rbeg = q * 16, rend = rbeg + 16;
        int rlim = E - e0;
        float run = 0.f;
        int cur = scol[rbeg];
        for (int row = rbeg; row < rend; ++row) {
            int cc = scol[row];
            float v = mbuf[(row << 7) + (jc ^ (((row >> 2) & 3) << 3))];
            if (cc != cur) {
                if (run != 0.f)
                    atomicAdd(&aggsum[(size_t)cur * H + jc], run * sinv[row - 1]);
                run = 0.f;
                cur = cc;
            }
            if (row < rlim) run += v;
        }
        if (run != 0.f)
            atomicAdd(&aggsum[(size_t)cur * H + jc], run * sinv[rend - 1]);
    }

    // fused e'-stats
    {
        float a = s1, b = s2;
        a += __shfl_xor(a, 16); a += __shfl_xor(a, 32);
        b += __shfl_xor(b, 16); b += __shfl_xor(b, 32);
        if (g == 0) {
            atomicAdd(&eStats[j], a);
            atomicAdd(&eStats[H + j], b);
        }
    }
}

// ---------------------------------------------------------------------------
// Node update, 512 threads: h = relu(bn_h(h)@V1 + aggmean@V2 + b2);
// fused h-stats; zeroes its aggsum rows.
__global__ __launch_bounds__(512, 4) void node_kernel(unsigned short* hb,
                                                      float* __restrict__ aggsum,
                                                      const short8* __restrict__ wfrL,
                                                      const float* __restrict__ b2, int M,
                                                      const float* __restrict__ Sh,
                                                      const float* __restrict__ gh,
                                                      const float* __restrict__ bh,
                                                      float invN,
                                                      float* __restrict__ hStats)
{
    __shared__ __align__(16) unsigned short sA[64 * 128];
    __shared__ __align__(16) unsigned short sB[64 * 128];
    __shared__ float bnp[256];
    const int t = threadIdx.x, lane = t & 63, w = t >> 6;
    const int r0 = blockIdx.x * 64;
    const int g = lane >> 4, c0 = lane & 15;
    const int j = 16 * w + c0;
    if (t < 128) bn_param(Sh, gh, bh, invN, t, bnp, bnp + 128);
    __syncthreads();
    stage_aff(hb, sA, r0, M, t, bnp, bnp + 128);
    stage_agg_bf16(aggsum, sB, r0, M, t);   // also zeroes consumed rows
    short8 wf[4];
    f32x4 acc[4];
    zero_acc_h(acc);
    load_wfrag_h(wfrL + 5 * 2048, w, lane, wf);   // V1
    __syncthreads();
    mfma_gemm_h(sA, wf, acc, lane);
    load_wfrag_h(wfrL + 6 * 2048, w, lane, wf);   // V2
    mfma_gemm_h(sB, wf, acc, lane);
    float s1 = 0.f, s2 = 0.f;
    {
        float bj = b2[j];
#pragma unroll
        for (int fr = 0; fr < 4; ++fr)
#pragma unroll
            for (int r = 0; r < 4; ++r) {
                int row = r0 + 16 * fr + 4 * g + r;
                if (row < M) {
                    float v = fmaxf(acc[fr][r] + bj, 0.f);
                    hb[(size_t)row * H + j] = f2bf(v);
                    s1 += v;
                    s2 += v * v;
                }
            }
    }
    {
        float a = s1, b = s2;
        a += __shfl_xor(a, 16); a += __shfl_xor(a, 32);
        b += __shfl_xor(b, 16); b += __shfl_xor(b, 32);
        if (g == 0) {
            atomicAdd(&hStats[j], a);
            atomicAdd(&hStats[H + j], b);
        }
    }
}

// ---------------------------------------------------------------------------
// Final readout: out = [mean(h) | mean(e)] @ reg_w + reg_b
__global__ __launch_bounds__(256) void final_kernel(const float* __restrict__ hsum,
                                                    const float* __restrict__ esum,
                                                    const float* __restrict__ reg_w,
                                                    const float* __restrict__ reg_b,
                                                    float* __restrict__ out,
                                                    float invN, float invE)
{
    __shared__ float red[256];
    int t = threadIdx.x;
    float v = (t < 128) ? hsum[t] * invN * reg_w[t]
                        : esum[t - 128] * invE * reg_w[t];
    red[t] = v;
    __syncthreads();
    for (int s = 128; s > 0; s >>= 1) {
        if (t < s) red[t] += red[t + s];
        __syncthreads();
    }
    if (t == 0) out[0] = red[0] + reg_b[0];
}

// ---------------------------------------------------------------------------
extern "C" void kernel_launch(void* const* d_in, const int* in_sizes, int n_in,
                              void* d_out, int out_size, void* d_ws, size_t ws_size,
                              hipStream_t stream)
{
    const float* x          = (const float*)d_in[0];
    const int*   edge_index = (const int*)  d_in[1];
    const float* edge_attr  = (const float*)d_in[2];
    const float* enc_node_w = (const float*)d_in[3];
    const float* enc_node_b = (const float*)d_in[4];
    const float* enc_edge_w = (const float*)d_in[5];
    const float* enc_edge_b = (const float*)d_in[6];
    const float* edge_w     = (const float*)d_in[7];
    const float* edge_b     = (const float*)d_in[8];
    const float* n1_w       = (const float*)d_in[9];
    const float* n1_b       = (const float*)d_in[10];
    const float* n2_w       = (const float*)d_in[11];
    const float* n2_b       = (const float*)d_in[12];
    const float* bn_node_g  = (const float*)d_in[13];
    const float* bn_node_b  = (const float*)d_in[14];
    const float* bn_edge_g  = (const float*)d_in[15];
    const float* bn_edge_b  = (const float*)d_in[16];
    const float* reg_w      = (const float*)d_in[17];
    const float* reg_b      = (const float*)d_in[18];

    const int N = in_sizes[0] / F_IN;
    const int E = in_sizes[1] / 2;
    const size_t NH = (size_t)N * H;
    const size_t EH = (size_t)E * H;

    // Workspace layout: one contiguous zero region up front.
    float* ws     = (float*)d_ws;
    float* aggsum = ws;                     // [N,128] f32
    float* stats  = aggsum + NH;            // 3 * 512 (S0,S1,S2, per-layer)
    int*   cnt_i  = (int*)(stats + 1536);   // [N]
    int*   tmpc   = cnt_i + N;              // [N]
    const size_t zeroFloats = NH + 1536 + 2 * (size_t)N;
    int*   offs   = tmpc + N;               // [N+1]
    int*   bsum   = offs + N + 1;           // [1024]
    int*   sortedIds = bsum + 1024;         // [E]
    int*   rowS   = sortedIds + E;          // [E]
    int*   colS   = rowS + E;               // [E]
    short8* wfr   = (short8*)((((uintptr_t)(colS + E)) + 15) & ~(uintptr_t)15);  // 21*2048
    unsigned short* hbuf = (unsigned short*)(wfr + 21 * 2048);  // [N,128] bf16
    unsigned short* ebuf = hbuf + NH;                           // [E,128] bf16 (col-sorted)

    const int* row_idx = edge_index;
    const int* col_idx = edge_index + E;
    const float invN = 1.f / (float)N;
    const float invE = 1.f / (float)E;
    const int nb = (N + 1023) / 1024;       // scan chunks (<=1024 for N<=1M)

    // one-time: single upfront memset; sort edges by col (parallel scan);
    // bf16 weight fragments; encoders
    (void)hipMemsetAsync(aggsum, 0, zeroFloats * sizeof(float), stream);
    hist_kernel<<<(E + 255) / 256, 256, 0, stream>>>(col_idx, cnt_i, E);
    scanA_kernel<<<nb, 256, 0, stream>>>(cnt_i, offs, bsum, N);
    scanB_kernel<<<1, 1024, 0, stream>>>(bsum, nb);
    scanC_kernel<<<nb, 256, 0, stream>>>(offs, bsum, N);
    scatter_kernel<<<(E + 255) / 256, 256, 0, stream>>>(row_idx, col_idx, offs, tmpc,
                                                        sortedIds, rowS, colS, E);
    wbf16_kernel<<<21, 256, 0, stream>>>(edge_w, n1_w, n2_w, wfr);

    enc_kernel<<<(N + 1) / 2, 256, 0, stream>>>(x, enc_node_w, enc_node_b, hbuf, N);
    enc_gather_kernel<<<(E + 1) / 2, 256, 0, stream>>>(edge_attr, sortedIds,
                                                       enc_edge_w, enc_edge_b, ebuf, E);

    const int nodeBlocks = (N + 63) / 64;
    const int edgeBlocks = (E + 63) / 64;

    for (int i = 0; i < 3; ++i) {
        float*       Scur  = stats + (size_t)i * 512;          // zeroed upfront
        const float* Sprev = (i == 0) ? nullptr : stats + (size_t)(i - 1) * 512;
        const float* Sh = Sprev;
        const float* Se = Sprev ? Sprev + 256 : nullptr;
        const short8* wfrL = wfr + (size_t)i * 7 * 2048;
        edge_kernel<<<edgeBlocks, 512, 0, stream>>>(
            ebuf, rowS, colS, cnt_i, hbuf, wfrL,
            edge_b + i * H, n1_b + i * H,
            aggsum, E,
            Sh, bn_node_g, bn_node_b, invN,
            Se, bn_edge_g, bn_edge_b, invE,
            Scur + 256);
        node_kernel<<<nodeBlocks, 512, 0, stream>>>(
            hbuf, aggsum, wfrL, n2_b + i * H, N,
            Sh, bn_node_g, bn_node_b, invN,
            Scur);
    }
    // layer 2 wrote stats+1024 (S2)
    final_kernel<<<1, 256, 0, stream>>>(stats + 1024, stats + 1024 + 256, reg_w, reg_b,
                                        (float*)d_out, invN, invE);
}

// Round 26
// 642.695 us; speedup vs baseline: 1.2359x; 1.0037x over previous
//
#include <hip/hip_runtime.h>

#define H 128
#define F_IN 16
#define BNEPS 1e-5f

typedef __attribute__((ext_vector_type(8))) short short8;
typedef __attribute__((ext_vector_type(4))) float f32x4;

// f32 -> bf16 round-to-nearest-even
__device__ __forceinline__ unsigned short f2bf(float f)
{
    unsigned u = __builtin_bit_cast(unsigned, f);
    u += 0x7FFFu + ((u >> 16) & 1u);
    return (unsigned short)(u >> 16);
}
__device__ __forceinline__ float bf2f(unsigned short h)
{
    return __builtin_bit_cast(float, (unsigned)h << 16);
}

// BN affine params for feature j: s[j], t[j] (identity if S==nullptr)
__device__ __forceinline__ void bn_param(const float* __restrict__ S,
                                         const float* __restrict__ g,
                                         const float* __restrict__ b,
                                         float invM, int j,
                                         float* __restrict__ sS, float* __restrict__ sT)
{
    float s = 1.f, tt = 0.f;
    if (S) {
        float mean = S[j] * invM;
        float var  = S[H + j] * invM - mean * mean;
        s  = rsqrtf(var + BNEPS) * g[j];
        tt = b[j] - mean * s;
    }
    sS[j] = s;
    sT[j] = tt;
}

// ---------------------------------------------------------------------------
// 512-thread staging: 64x128 bf16 tile with per-feature affine into swizzled
// LDS. element (row,k) -> ushort idx row*128 + (k ^ ((row&7)<<3))
__device__ __forceinline__ void stage_aff(const unsigned short* __restrict__ src,
                                          unsigned short* sA, int r0, int M, int t,
                                          const float* __restrict__ sS,
                                          const float* __restrict__ sT)
{
#pragma unroll
    for (int i = 0; i < 2; ++i) {
        int cid  = t + 512 * i;
        int row  = cid >> 4;
        int ck   = cid & 15;
        int grow = r0 + row;
        short8 v = (short8)0;
        if (grow < M) {
            v = *(const short8*)(src + (size_t)grow * H + ck * 8);
            int j0 = ck * 8;
#pragma unroll
            for (int j = 0; j < 8; ++j)
                v[j] = (short)f2bf(bf2f((unsigned short)v[j]) * sS[j0 + j] + sT[j0 + j]);
        }
        *(short8*)(sA + (row << 7) + ((ck ^ (row & 7)) << 3)) = v;
    }
}

// Gather variant: tile row i holds src[idx[p0+i]], same affine.
__device__ __forceinline__ void stage_aff_gather(const unsigned short* __restrict__ src,
                                                 const int* __restrict__ idx,
                                                 unsigned short* sA, int p0, int M, int t,
                                                 const float* __restrict__ sS,
                                                 const float* __restrict__ sT)
{
#pragma unroll
    for (int i = 0; i < 2; ++i) {
        int cid = t + 512 * i;
        int row = cid >> 4;
        int ck  = cid & 15;
        int p   = p0 + row;
        short8 v = (short8)0;
        if (p < M) {
            v = *(const short8*)(src + (size_t)idx[p] * H + ck * 8);
            int j0 = ck * 8;
#pragma unroll
            for (int j = 0; j < 8; ++j)
                v[j] = (short)f2bf(bf2f((unsigned short)v[j]) * sS[j0 + j] + sT[j0 + j]);
        }
        *(short8*)(sA + (row << 7) + ((ck ^ (row & 7)) << 3)) = v;
    }
}

// aggsum holds per-node MEANS -> convert to bf16; then zero rows for next layer
__device__ __forceinline__ void stage_agg_bf16(float* __restrict__ aggsum,
                                               unsigned short* sA, int r0, int M, int t)
{
#pragma unroll
    for (int i = 0; i < 2; ++i) {
        int cid  = t + 512 * i;
        int row  = cid >> 4;
        int ck   = cid & 15;
        int grow = r0 + row;
        short8 ph = (short8)0;
        if (grow < M) {
            float4* q = (float4*)(aggsum + (size_t)grow * H + ck * 8);
            float4 a = q[0], b = q[1];
            float xs[8] = {a.x, a.y, a.z, a.w, b.x, b.y, b.z, b.w};
#pragma unroll
            for (int j = 0; j < 8; ++j) ph[j] = (short)f2bf(xs[j]);
            q[0] = make_float4(0.f, 0.f, 0.f, 0.f);
            q[1] = make_float4(0.f, 0.f, 0.f, 0.f);
        }
        *(short8*)(sA + (row << 7) + ((ck ^ (row & 7)) << 3)) = ph;
    }
}

// ---------------------------------------------------------------------------
// One-time weight bf16 fragment precompute (21 matrices, unscaled).
__global__ __launch_bounds__(256) void wbf16_kernel(const float* __restrict__ edge_w,
                                                    const float* __restrict__ n1_w,
                                                    const float* __restrict__ n2_w,
                                                    short8* __restrict__ out)
{
    int m = blockIdx.x;
    int layer = m / 7, k = m % 7;
    const float* W = (k < 3) ? edge_w + (size_t)layer * 384 * H + (size_t)k * H * H
                   : (k < 5) ? n1_w + (size_t)layer * 256 * H + (size_t)(k - 3) * H * H
                             : n2_w + (size_t)layer * 256 * H + (size_t)(k - 5) * H * H;
    short8* oh = out + (size_t)m * 2048;
    for (int e = threadIdx.x; e < 2048; e += 256) {
        int jbB = e >> 9, s = (e >> 7) & 3, c = (e >> 6) & 1, lane = e & 63;
        int g = lane >> 4, c0 = lane & 15;
        short8 hi;
#pragma unroll
        for (int j = 0; j < 8; ++j)
            hi[j] = (short)f2bf(W[(size_t)(32 * s + 8 * g + j) * H + jbB * 32 + 16 * c + c0]);
        oh[e] = hi;
    }
}

// Wave w (0..7) owns cols [16w,16w+16): fragment idx jbB=w>>1, cB=w&1.
__device__ __forceinline__ void load_wfrag_h(const short8* __restrict__ Wp, int w,
                                             int lane, short8 wf[4])
{
    int base = ((w >> 1) * 8 + (w & 1)) * 64 + lane;
#pragma unroll
    for (int s = 0; s < 4; ++s)
        wf[s] = Wp[base + s * 128];
}

// acc[fr] += sA(64x128 bf16, swizzled) @ Wf(128x16 bf16)   (16 MFMA)
__device__ __forceinline__ void mfma_gemm_h(const unsigned short* sA, const short8 wf[4],
                                            f32x4 acc[4], int lane)
{
    const int g = lane >> 4, r = lane & 15;
#pragma unroll
    for (int s = 0; s < 4; ++s) {
        short8 a4[4];
#pragma unroll
        for (int fr = 0; fr < 4; ++fr) {
            int row = 16 * fr + r;
            int ck  = (4 * s + g) ^ (row & 7);
            a4[fr] = *(const short8*)(sA + (row << 7) + (ck << 3));
        }
#pragma unroll
        for (int fr = 0; fr < 4; ++fr)
            acc[fr] = __builtin_amdgcn_mfma_f32_16x16x32_bf16(a4[fr], wf[s], acc[fr], 0, 0, 0);
    }
}

__device__ __forceinline__ void zero_acc_h(f32x4 acc[4])
{
#pragma unroll
    for (int fr = 0; fr < 4; ++fr) {
        acc[fr][0] = 0.f; acc[fr][1] = 0.f; acc[fr][2] = 0.f; acc[fr][3] = 0.f;
    }
}

// ---------------------------------------------------------------------------
// One-time sort machinery (edge_index is layer-invariant)
__global__ __launch_bounds__(256) void hist_kernel(const int* __restrict__ col,
                                                   int* __restrict__ cnt, int E)
{
    int e = blockIdx.x * 256 + threadIdx.x;
    if (e < E) atomicAdd(&cnt[col[e]], 1);
}

// Parallel 3-phase exclusive scan over cnt[0..Nn) -> offs.
__global__ __launch_bounds__(256) void scanA_kernel(const int* __restrict__ cnt,
                                                    int* __restrict__ offs,
                                                    int* __restrict__ bsum, int Nn)
{
    __shared__ int ls[256];
    int b = blockIdx.x, t = threadIdx.x;
    int base = b * 1024 + t * 4;
    int v0 = (base + 0 < Nn) ? cnt[base + 0] : 0;
    int v1 = (base + 1 < Nn) ? cnt[base + 1] : 0;
    int v2 = (base + 2 < Nn) ? cnt[base + 2] : 0;
    int v3 = (base + 3 < Nn) ? cnt[base + 3] : 0;
    int s = v0 + v1 + v2 + v3;
    ls[t] = s;
    __syncthreads();
    for (int d = 1; d < 256; d <<= 1) {
        int u = (t >= d) ? ls[t - d] : 0;
        __syncthreads();
        ls[t] += u;
        __syncthreads();
    }
    int run = ls[t] - s;
    if (t == 255) bsum[b] = ls[255];
    if (base + 0 < Nn) { offs[base + 0] = run; run += v0; }
    if (base + 1 < Nn) { offs[base + 1] = run; run += v1; }
    if (base + 2 < Nn) { offs[base + 2] = run; run += v2; }
    if (base + 3 < Nn) { offs[base + 3] = run; run += v3; }
}

__global__ __launch_bounds__(1024) void scanB_kernel(int* __restrict__ bsum, int nb)
{
    __shared__ int ls[1024];
    int t = threadIdx.x;
    int s = (t < nb) ? bsum[t] : 0;
    ls[t] = s;
    __syncthreads();
    for (int d = 1; d < 1024; d <<= 1) {
        int u = (t >= d) ? ls[t - d] : 0;
        __syncthreads();
        ls[t] += u;
        __syncthreads();
    }
    if (t < nb) bsum[t] = ls[t] - s;
}

__global__ __launch_bounds__(256) void scanC_kernel(int* __restrict__ offs,
                                                    const int* __restrict__ bsum, int Nn)
{
    int b = blockIdx.x;
    int add = bsum[b];
    int base = b * 1024 + threadIdx.x * 4;
#pragma unroll
    for (int k = 0; k < 4; ++k)
        if (base + k < Nn) offs[base + k] += add;
}

__global__ __launch_bounds__(256) void scatter_kernel(const int* __restrict__ row,
                                                      const int* __restrict__ col,
                                                      const int* __restrict__ offs,
                                                      int* __restrict__ tmpc,
                                                      int* __restrict__ sortedIds,
                                                      int* __restrict__ rowS,
                                                      int* __restrict__ colS, int E)
{
    int e = blockIdx.x * 256 + threadIdx.x;
    if (e < E) {
        int c = col[e];
        int p = offs[c] + atomicAdd(&tmpc[c], 1);
        sortedIds[p] = e;
        rowS[p] = row[e];
        colS[p] = c;
    }
}

// ---------------------------------------------------------------------------
// Encoder: out(bf16) = relu(X[M,16] @ W[16,128] + b)
__global__ __launch_bounds__(256) void enc_kernel(const float* __restrict__ X,
                                                  const float* __restrict__ W,
                                                  const float* __restrict__ bias,
                                                  unsigned short* __restrict__ out, int M)
{
    __shared__ float sW[F_IN * H];
    __shared__ float sb[H];
    int t = threadIdx.x;
    reinterpret_cast<float4*>(sW)[t]       = reinterpret_cast<const float4*>(W)[t];
    reinterpret_cast<float4*>(sW)[t + 256] = reinterpret_cast<const float4*>(W)[t + 256];
    if (t < H) sb[t] = bias[t];
    __syncthreads();
    int row = blockIdx.x * 2 + (t >> 7);
    if (row >= M) return;
    int j = t & 127;
    float acc = sb[j];
#pragma unroll
    for (int k = 0; k < F_IN; ++k)
        acc += X[(size_t)row * F_IN + k] * sW[k * H + j];
    out[(size_t)row * H + j] = f2bf(fmaxf(acc, 0.f));
}

// Gather-encoder: out[p](bf16) = relu(X[sortedIds[p],16] @ W + b)
__global__ __launch_bounds__(256) void enc_gather_kernel(const float* __restrict__ X,
                                                         const int* __restrict__ sortedIds,
                                                         const float* __restrict__ W,
                                                         const float* __restrict__ bias,
                                                         unsigned short* __restrict__ out,
                                                         int M)
{
    __shared__ float sW[F_IN * H];
    __shared__ float sb[H];
    int t = threadIdx.x;
    reinterpret_cast<float4*>(sW)[t]       = reinterpret_cast<const float4*>(W)[t];
    reinterpret_cast<float4*>(sW)[t + 256] = reinterpret_cast<const float4*>(W)[t + 256];
    if (t < H) sb[t] = bias[t];
    __syncthreads();
    int p = blockIdx.x * 2 + (t >> 7);
    if (p >= M) return;
    int src = sortedIds[p];
    int j = t & 127;
    float acc = sb[j];
#pragma unroll
    for (int k = 0; k < F_IN; ++k)
        acc += X[(size_t)src * F_IN + k] * sW[k * H + j];
    out[(size_t)p * H + j] = f2bf(fmaxf(acc, 0.f));
}

// ---------------------------------------------------------------------------
// Fused edge kernel, 512 threads (8 waves x 16-col strips):
//   e'[p] = relu(bn_e(e[p])@W3 + bn_h(h[rowS])@W1 + bn_h(h[colS])@W2 + be)
//   m     = relu(e'@U2 + bn_h(h[rowS])@U1 + b1)
//   aggsum[col] += segment-MEAN partials (mbuf, 4-way) ; fused e'-stats
//   e' written to global via coalesced LDS stage-out.
__global__ __launch_bounds__(512, 3) void edge_kernel(unsigned short* eb,
                                                      const int* __restrict__ rowS,
                                                      const int* __restrict__ colS,
                                                      const int* __restrict__ cnt,
                                                      const unsigned short* __restrict__ hb,
                                                      const short8* __restrict__ wfrL,
                                                      const float* __restrict__ be,
                                                      const float* __restrict__ b1,
                                                      float* __restrict__ aggsum, int E,
                                                      const float* __restrict__ Sh,
                                                      const float* __restrict__ gh,
                                                      const float* __restrict__ bh,
                                                      float invN,
                                                      const float* __restrict__ Se,
                                                      const float* __restrict__ ge,
                                                      const float* __restrict__ beB,
                                                      float invE,
                                                      float* __restrict__ eStats)
{
    __shared__ __align__(16) unsigned char smem[64 * 128 * 6 + 256 + 256 + 2048];
    unsigned short* sE  = (unsigned short*)smem;          // 16 KB  e (bf16)
    unsigned short* sHt = sE + 64 * 128;                  // 16 KB  h[rowS] (bf16)
    unsigned short* sHc = sHt + 64 * 128;                 // 16 KB  h[colS] (bf16)
    float*          mbuf = (float*)smem;                  // 32 KB overlay sE+sHt
    int*            scol = (int*)(smem + 64 * 128 * 6);          // 256 B
    float*          sinv = (float*)(smem + 64 * 128 * 6 + 256);  // 256 B
    float*          bnp  = (float*)(smem + 64 * 128 * 6 + 512);  // 2 KB

    const int t = threadIdx.x, lane = t & 63, w = t >> 6;
    const int e0 = blockIdx.x * 64;
    const int g = lane >> 4, c0 = lane & 15;
    const int j = 16 * w + c0;        // this lane's output column

    if (t < 64) {
        int cc = colS[(e0 + t < E) ? (e0 + t) : (E - 1)];
        scol[t] = cc;
        int c = cnt[cc];
        sinv[t] = 1.f / (float)(c > 1 ? c : 1);
    }
    if (t >= 64 && t < 192)      bn_param(Sh, gh, bh, invN, t - 64, bnp, bnp + 128);
    else if (t >= 192 && t < 320) bn_param(Se, ge, beB, invE, t - 192, bnp + 256, bnp + 384);
    __syncthreads();   // bnp + scol ready

    stage_aff(eb, sE, e0, E, t, bnp + 256, bnp + 384);
    stage_aff_gather(hb, rowS, sHt, e0, E, t, bnp, bnp + 128);
    {
        int Mt = E - e0; if (Mt > 64) Mt = 64;
        stage_aff_gather(hb, scol, sHc, 0, Mt, t, bnp, bnp + 128);
    }

    short8 wf[4];
    f32x4 acc[4];
    zero_acc_h(acc);
    load_wfrag_h(wfrL + 2 * 2048, w, lane, wf);   // W3
    __syncthreads();
    mfma_gemm_h(sE, wf, acc, lane);
    load_wfrag_h(wfrL + 0 * 2048, w, lane, wf);   // W1
    mfma_gemm_h(sHt, wf, acc, lane);
    load_wfrag_h(wfrL + 1 * 2048, w, lane, wf);   // W2 (B-term)
    mfma_gemm_h(sHc, wf, acc, lane);
    __syncthreads();   // all reads of sE done -> safe to overwrite with e'

    // epilogue 1: e' = relu(acc + be) -> sE (swizzled) + stats in registers
    float s1 = 0.f, s2 = 0.f;
    {
        float bej = be[j];
#pragma unroll
        for (int fr = 0; fr < 4; ++fr)
#pragma unroll
            for (int r = 0; r < 4; ++r) {
                int Rl = 16 * fr + 4 * g + r;
                int p  = e0 + Rl;
                float v = acc[fr][r] + bej;
                v = fmaxf(v, 0.f);
                unsigned short vb = f2bf(v);
                if (p < E) {
                    s1 += v;
                    s2 += v * v;
                }
                sE[(Rl << 7) + (j ^ ((Rl & 7) << 3))] = vb;
            }
    }
    __syncthreads();   // sE complete

    // coalesced e' stage-out: 2 x 16B stores per thread (reads sE, unswizzled)
#pragma unroll
    for (int i = 0; i < 2; ++i) {
        int cid = t + 512 * i;
        int row = cid >> 4;
        int ck  = cid & 15;
        int p   = e0 + row;
        if (p < E) {
            short8 v = *(const short8*)(sE + (row << 7) + ((ck ^ (row & 7)) << 3));
            *(short8*)(eb + (size_t)p * H + ck * 8) = v;
        }
    }

    // GEMM2: m = e'@U2 + bn_h(h[rowS])@U1
    zero_acc_h(acc);
    load_wfrag_h(wfrL + 4 * 2048, w, lane, wf);   // U2
    mfma_gemm_h(sE, wf, acc, lane);
    load_wfrag_h(wfrL + 3 * 2048, w, lane, wf);   // U1
    mfma_gemm_h(sHt, wf, acc, lane);
    __syncthreads();   // all GEMM2 LDS reads done -> mbuf overlay safe

    // epilogue 2: m -> mbuf (swizzled)
    {
        float b1j = b1[j];
#pragma unroll
        for (int fr = 0; fr < 4; ++fr)
#pragma unroll
            for (int r = 0; r < 4; ++r) {
                int Rl = 16 * fr + 4 * g + r;
                float v = fmaxf(acc[fr][r] + b1j, 0.f);
                mbuf[(Rl << 7) + (j ^ (((Rl >> 2) & 3) << 3))] = v;
            }
    }
    __syncthreads();

    // segmented reduction, 4-way parallel over row quarters (512 threads)
    {
        int jc = t & 127, q = t >> 7;
        int rbeg = q * 16, rend = rbeg + 16;
        int rlim = E - e0;
        float run = 0.f;
        int cur = scol[rbeg];
        for (int row = rbeg; row < rend; ++row) {
            int cc = scol[row];
            float v = mbuf[(row << 7) + (jc ^ (((row >> 2) & 3) << 3))];
            if (cc != cur) {
                if (run != 0.f)
                    atomicAdd(&aggsum[(size_t)cur * H + jc], run * sinv[row - 1]);
                run = 0.f;
                cur = cc;
            }
            if (row < rlim) run += v;
        }
        if (run != 0.f)
            atomicAdd(&aggsum[(size_t)cur * H + jc], run * sinv[rend - 1]);
    }

    // fused e'-stats
    {
        float a = s1, b = s2;
        a += __shfl_xor(a, 16); a += __shfl_xor(a, 32);
        b += __shfl_xor(b, 16); b += __shfl_xor(b, 32);
        if (g == 0) {
            atomicAdd(&eStats[j], a);
            atomicAdd(&eStats[H + j], b);
        }
    }
}

// ---------------------------------------------------------------------------
// Node update, 512 threads: h = relu(bn_h(h)@V1 + aggmean@V2 + b2);
// fused h-stats; zeroes its aggsum rows.
__global__ __launch_bounds__(512, 4) void node_kernel(unsigned short* hb,
                                                      float* __restrict__ aggsum,
                                                      const short8* __restrict__ wfrL,
                                                      const float* __restrict__ b2, int M,
                                                      const float* __restrict__ Sh,
                                                      const float* __restrict__ gh,
                                                      const float* __restrict__ bh,
                                                      float invN,
                                                      float* __restrict__ hStats)
{
    __shared__ __align__(16) unsigned short sA[64 * 128];
    __shared__ __align__(16) unsigned short sB[64 * 128];
    __shared__ float bnp[256];
    const int t = threadIdx.x, lane = t & 63, w = t >> 6;
    const int r0 = blockIdx.x * 64;
    const int g = lane >> 4, c0 = lane & 15;
    const int j = 16 * w + c0;
    if (t < 128) bn_param(Sh, gh, bh, invN, t, bnp, bnp + 128);
    __syncthreads();
    stage_aff(hb, sA, r0, M, t, bnp, bnp + 128);
    stage_agg_bf16(aggsum, sB, r0, M, t);   // also zeroes consumed rows
    short8 wf[4];
    f32x4 acc[4];
    zero_acc_h(acc);
    load_wfrag_h(wfrL + 5 * 2048, w, lane, wf);   // V1
    __syncthreads();
    mfma_gemm_h(sA, wf, acc, lane);
    load_wfrag_h(wfrL + 6 * 2048, w, lane, wf);   // V2
    mfma_gemm_h(sB, wf, acc, lane);
    float s1 = 0.f, s2 = 0.f;
    {
        float bj = b2[j];
#pragma unroll
        for (int fr = 0; fr < 4; ++fr)
#pragma unroll
            for (int r = 0; r < 4; ++r) {
                int row = r0 + 16 * fr + 4 * g + r;
                if (row < M) {
                    float v = fmaxf(acc[fr][r] + bj, 0.f);
                    hb[(size_t)row * H + j] = f2bf(v);
                    s1 += v;
                    s2 += v * v;
                }
            }
    }
    {
        float a = s1, b = s2;
        a += __shfl_xor(a, 16); a += __shfl_xor(a, 32);
        b += __shfl_xor(b, 16); b += __shfl_xor(b, 32);
        if (g == 0) {
            atomicAdd(&hStats[j], a);
            atomicAdd(&hStats[H + j], b);
        }
    }
}

// ---------------------------------------------------------------------------
// Final readout: out = [mean(h) | mean(e)] @ reg_w + reg_b
__global__ __launch_bounds__(256) void final_kernel(const float* __restrict__ hsum,
                                                    const float* __restrict__ esum,
                                                    const float* __restrict__ reg_w,
                                                    const float* __restrict__ reg_b,
                                                    float* __restrict__ out,
                                                    float invN, float invE)
{
    __shared__ float red[256];
    int t = threadIdx.x;
    float v = (t < 128) ? hsum[t] * invN * reg_w[t]
                        : esum[t - 128] * invE * reg_w[t];
    red[t] = v;
    __syncthreads();
    for (int s = 128; s > 0; s >>= 1) {
        if (t < s) red[t] += red[t + s];
        __syncthreads();
    }
    if (t == 0) out[0] = red[0] + reg_b[0];
}

// ---------------------------------------------------------------------------
extern "C" void kernel_launch(void* const* d_in, const int* in_sizes, int n_in,
                              void* d_out, int out_size, void* d_ws, size_t ws_size,
                              hipStream_t stream)
{
    const float* x          = (const float*)d_in[0];
    const int*   edge_index = (const int*)  d_in[1];
    const float* edge_attr  = (const float*)d_in[2];
    const float* enc_node_w = (const float*)d_in[3];
    const float* enc_node_b = (const float*)d_in[4];
    const float* enc_edge_w = (const float*)d_in[5];
    const float* enc_edge_b = (const float*)d_in[6];
    const float* edge_w     = (const float*)d_in[7];
    const float* edge_b     = (const float*)d_in[8];
    const float* n1_w       = (const float*)d_in[9];
    const float* n1_b       = (const float*)d_in[10];
    const float* n2_w       = (const float*)d_in[11];
    const float* n2_b       = (const float*)d_in[12];
    const float* bn_node_g  = (const float*)d_in[13];
    const float* bn_node_b  = (const float*)d_in[14];
    const float* bn_edge_g  = (const float*)d_in[15];
    const float* bn_edge_b  = (const float*)d_in[16];
    const float* reg_w      = (const float*)d_in[17];
    const float* reg_b      = (const float*)d_in[18];

    const int N = in_sizes[0] / F_IN;
    const int E = in_sizes[1] / 2;
    const size_t NH = (size_t)N * H;
    const size_t EH = (size_t)E * H;

    // Workspace layout: one contiguous zero region up front; h/e rows 256B-aligned.
    float* ws     = (float*)d_ws;
    float* aggsum = ws;                     // [N,128] f32
    float* stats  = aggsum + NH;            // 3 * 512 (S0,S1,S2, per-layer)
    int*   cnt_i  = (int*)(stats + 1536);   // [N]
    int*   tmpc   = cnt_i + N;              // [N]
    const size_t zeroFloats = NH + 1536 + 2 * (size_t)N;
    int*   offs   = tmpc + N;               // [N+1]
    int*   bsum   = offs + N + 1;           // [1024]
    int*   sortedIds = bsum + 1024;         // [E]
    int*   rowS   = sortedIds + E;          // [E]
    int*   colS   = rowS + E;               // [E]
    // 256B-align wfr so hbuf/ebuf rows (256B each) are cache-line aligned
    short8* wfr   = (short8*)((((uintptr_t)(colS + E)) + 255) & ~(uintptr_t)255);
    unsigned short* hbuf = (unsigned short*)(wfr + 21 * 2048);  // [N,128] bf16 (256B-aligned)
    unsigned short* ebuf = hbuf + NH;                           // [E,128] bf16 (col-sorted)

    const int* row_idx = edge_index;
    const int* col_idx = edge_index + E;
    const float invN = 1.f / (float)N;
    const float invE = 1.f / (float)E;
    const int nb = (N + 1023) / 1024;       // scan chunks (<=1024 for N<=1M)

    // one-time: single upfront memset; sort edges by col (parallel scan);
    // bf16 weight fragments; encoders
    (void)hipMemsetAsync(aggsum, 0, zeroFloats * sizeof(float), stream);
    hist_kernel<<<(E + 255) / 256, 256, 0, stream>>>(col_idx, cnt_i, E);
    scanA_kernel<<<nb, 256, 0, stream>>>(cnt_i, offs, bsum, N);
    scanB_kernel<<<1, 1024, 0, stream>>>(bsum, nb);
    scanC_kernel<<<nb, 256, 0, stream>>>(offs, bsum, N);
    scatter_kernel<<<(E + 255) / 256, 256, 0, stream>>>(row_idx, col_idx, offs, tmpc,
                                                        sortedIds, rowS, colS, E);
    wbf16_kernel<<<21, 256, 0, stream>>>(edge_w, n1_w, n2_w, wfr);

    enc_kernel<<<(N + 1) / 2, 256, 0, stream>>>(x, enc_node_w, enc_node_b, hbuf, N);
    enc_gather_kernel<<<(E + 1) / 2, 256, 0, stream>>>(edge_attr, sortedIds,
                                                       enc_edge_w, enc_edge_b, ebuf, E);

    const int nodeBlocks = (N + 63) / 64;
    const int edgeBlocks = (E + 63) / 64;

    for (int i = 0; i < 3; ++i) {
        float*       Scur  = stats + (size_t)i * 512;          // zeroed upfront
        const float* Sprev = (i == 0) ? nullptr : stats + (size_t)(i - 1) * 512;
        const float* Sh = Sprev;
        const float* Se = Sprev ? Sprev + 256 : nullptr;
        const short8* wfrL = wfr + (size_t)i * 7 * 2048;
        edge_kernel<<<edgeBlocks, 512, 0, stream>>>(
            ebuf, rowS, colS, cnt_i, hbuf, wfrL,
            edge_b + i * H, n1_b + i * H,
            aggsum, E,
            Sh, bn_node_g, bn_node_b, invN,
            Se, bn_edge_g, bn_edge_b, invE,
            Scur + 256);
        node_kernel<<<nodeBlocks, 512, 0, stream>>>(
            hbuf, aggsum, wfrL, n2_b + i * H, N,
            Sh, bn_node_g, bn_node_b, invN,
            Scur);
    }
    // layer 2 wrote stats+1024 (S2)
    final_kernel<<<1, 256, 0, stream>>>(stats + 1024, stats + 1024 + 256, reg_w, reg_b,
                                        (float*)d_out, invN, invE);
}